// Round 1
// baseline (245.309 us; speedup 1.0000x reference)
//
#include <hip/hip_runtime.h>
#include <hip/hip_bf16.h>
#include <stdint.h>

#define B_    4
#define S_    4096
#define F_    1024
#define A_    512
#define A6_   3072
#define M_    16384   // B*S

typedef __attribute__((ext_vector_type(8))) __bf16 bf16x8;
typedef __attribute__((ext_vector_type(4))) float  f32x4;

// ---------- helpers ----------
__device__ __forceinline__ float bflo(unsigned int u) {
  union { unsigned int i; float f; } v; v.i = u << 16; return v.f;
}
__device__ __forceinline__ float bfhi(unsigned int u) {
  union { unsigned int i; float f; } v; v.i = u & 0xffff0000u; return v.f;
}
__device__ __forceinline__ float bf1(unsigned short u) {
  union { unsigned int i; float f; } v; v.i = ((unsigned int)u) << 16; return v.f;
}

typedef __attribute__((address_space(3))) unsigned int lds_uint;
typedef const __attribute__((address_space(1))) unsigned int glob_uint;
__device__ __forceinline__ void lds_load16(const void* g, void* l) {
  __builtin_amdgcn_global_load_lds((glob_uint*)g, (lds_uint*)l, 16, 0, 0);
}

// ---------- K1: f32 -> bf16 conversion of inp and W ----------
__global__ void convert_kernel(const float* __restrict__ inp, const float* __restrict__ W,
                               __hip_bfloat16* __restrict__ inp_bf,
                               __hip_bfloat16* __restrict__ w_bf) {
  const int n_inp4 = (M_ * F_) / 4;   // 4,194,304
  const int n_w4   = (A6_ * F_) / 4;  //   786,432
  int idx = blockIdx.x * blockDim.x + threadIdx.x;
  int gs  = gridDim.x * blockDim.x;
  for (int i = idx; i < n_inp4; i += gs) {
    float4 v = ((const float4*)inp)[i];
    ushort4 o;
    o.x = __builtin_bit_cast(unsigned short, __float2bfloat16(v.x));
    o.y = __builtin_bit_cast(unsigned short, __float2bfloat16(v.y));
    o.z = __builtin_bit_cast(unsigned short, __float2bfloat16(v.z));
    o.w = __builtin_bit_cast(unsigned short, __float2bfloat16(v.w));
    ((ushort4*)inp_bf)[i] = o;
  }
  for (int i = idx; i < n_w4; i += gs) {
    float4 v = ((const float4*)W)[i];
    ushort4 o;
    o.x = __builtin_bit_cast(unsigned short, __float2bfloat16(v.x));
    o.y = __builtin_bit_cast(unsigned short, __float2bfloat16(v.y));
    o.z = __builtin_bit_cast(unsigned short, __float2bfloat16(v.z));
    o.w = __builtin_bit_cast(unsigned short, __float2bfloat16(v.w));
    ((ushort4*)w_bf)[i] = o;
  }
}

// ---------- K2: bf16 GEMM  X[M,3072] = A[M,1024] @ W[3072,1024]^T + b ----------
// m97 structure: 128x128 tile, BK=32, 4 waves (2x2), global_load_lds width 16.
__global__ __launch_bounds__(256) void gemm_kernel(
    const __hip_bfloat16* __restrict__ Abf,
    const __hip_bfloat16* __restrict__ Wbf,
    const float* __restrict__ bias,
    __hip_bfloat16* __restrict__ X) {
  __shared__ unsigned short ldsA[128 * 32];
  __shared__ unsigned short ldsB[128 * 32];

  int bid = blockIdx.x;
  // XCD-aware swizzle: 3072 blocks % 8 == 0 -> simple bijective remap
  int swz = (bid & 7) * 384 + (bid >> 3);
  const int NBLK = A6_ / 128;  // 24
  int mb = swz / NBLK;
  int nb = swz % NBLK;

  int tid  = threadIdx.x;
  int lane = tid & 63;
  int wv   = tid >> 6;
  int wm   = wv >> 1;   // 0..1
  int wn   = wv & 1;    // 0..1

  f32x4 acc[4][4];
#pragma unroll
  for (int i = 0; i < 4; i++)
#pragma unroll
    for (int j = 0; j < 4; j++) acc[i][j] = (f32x4){0.f, 0.f, 0.f, 0.f};

  int p0 = wv * 128 + lane;      // LDS 16B-unit index for this lane, i=0
  int r0 = p0 >> 2, ks0 = p0 & 3;
  int p1 = p0 + 64;
  int r1 = p1 >> 2, ks1 = p1 & 3;

  const __hip_bfloat16* Ab = Abf + (size_t)mb * 128 * F_;
  const __hip_bfloat16* Bb = Wbf + (size_t)nb * 128 * F_;

  for (int kt = 0; kt < F_ / 32; ++kt) {
    int kof = kt * 32;
    // stage A (8KB) + B (8KB): 4 wave-loads per wave
    lds_load16(Ab + (size_t)r0 * F_ + kof + ks0 * 8, &ldsA[(wv * 128) * 8]);
    lds_load16(Ab + (size_t)r1 * F_ + kof + ks1 * 8, &ldsA[(wv * 128 + 64) * 8]);
    lds_load16(Bb + (size_t)r0 * F_ + kof + ks0 * 8, &ldsB[(wv * 128) * 8]);
    lds_load16(Bb + (size_t)r1 * F_ + kof + ks1 * 8, &ldsB[(wv * 128 + 64) * 8]);
    __syncthreads();  // drains vmcnt before barrier

    bf16x8 af[4], bfr[4];
#pragma unroll
    for (int i = 0; i < 4; i++) {
      af[i]  = *(const bf16x8*)&ldsA[(wm * 64 + i * 16 + (lane & 15)) * 32 + (lane >> 4) * 8];
      bfr[i] = *(const bf16x8*)&ldsB[(wn * 64 + i * 16 + (lane & 15)) * 32 + (lane >> 4) * 8];
    }
#pragma unroll
    for (int i = 0; i < 4; i++)
#pragma unroll
      for (int j = 0; j < 4; j++)
        acc[i][j] = __builtin_amdgcn_mfma_f32_16x16x32_bf16(af[i], bfr[j], acc[i][j], 0, 0, 0);
    __syncthreads();
  }

  // epilogue: + bias, f32 -> bf16, store
#pragma unroll
  for (int i = 0; i < 4; i++) {
    int grow_base = mb * 128 + wm * 64 + i * 16 + (lane >> 4) * 4;
#pragma unroll
    for (int j = 0; j < 4; j++) {
      int gcol = nb * 128 + wn * 64 + j * 16 + (lane & 15);
      float bv = bias[gcol];
#pragma unroll
      for (int rg = 0; rg < 4; rg++) {
        int grow = grow_base + rg;
        X[(size_t)grow * A6_ + gcol] = __float2bfloat16(acc[i][j][rg] + bv);
      }
    }
  }
}

// ---------- K3a: agg[b,a] = mean_s qry ----------
__global__ void agg_kernel(const unsigned short* __restrict__ X, float* __restrict__ agg) {
  int b = blockIdx.z, half = blockIdx.y, chunk = blockIdx.x;
  int col = half * 256 + threadIdx.x;
  size_t base = ((size_t)b * S_ + chunk * 256) * A6_ + col;  // qry offset 0
  float sum = 0.f;
  for (int s = 0; s < 256; s++) sum += bf1(X[base + (size_t)s * A6_]);
  atomicAdd(&agg[b * A_ + col], sum * (1.f / S_));
}

// ---------- K3b: scores[b,s] = agg[b,:] . key[b,s,:] ----------
__global__ void scores_kernel(const unsigned short* __restrict__ X,
                              const float* __restrict__ agg,
                              float* __restrict__ scores) {
  int tid = threadIdx.x;
  int lane = tid & 63;
  int row = blockIdx.x * 4 + (tid >> 6);  // [0, 16384)
  int b = row >> 12;
  const float4* ap = (const float4*)&agg[b * A_ + lane * 8];
  float4 a0 = ap[0], a1 = ap[1];
  uint4 kv = *(const uint4*)&X[(size_t)row * A6_ + A_ + lane * 8];
  float s = a0.x * bflo(kv.x) + a0.y * bfhi(kv.x) +
            a0.z * bflo(kv.y) + a0.w * bfhi(kv.y) +
            a1.x * bflo(kv.z) + a1.y * bfhi(kv.z) +
            a1.z * bflo(kv.w) + a1.w * bfhi(kv.w);
  for (int off = 32; off; off >>= 1) s += __shfl_down(s, off);
  if (lane == 0) scores[row] = s;
}

// ---------- K3c: softmax over s (per b), in place ----------
__global__ void softmax_kernel(float* __restrict__ sc) {
  __shared__ float red[256];
  int b = blockIdx.x, t = threadIdx.x;
  float* p = sc + b * S_;
  float vals[16];
  float m = -1e30f;
#pragma unroll
  for (int i = 0; i < 16; i++) { vals[i] = p[t + i * 256]; m = fmaxf(m, vals[i]); }
  red[t] = m; __syncthreads();
  for (int o = 128; o; o >>= 1) { if (t < o) red[t] = fmaxf(red[t], red[t + o]); __syncthreads(); }
  m = red[0]; __syncthreads();
  float sum = 0.f;
#pragma unroll
  for (int i = 0; i < 16; i++) { vals[i] = __expf(vals[i] - m); sum += vals[i]; }
  red[t] = sum; __syncthreads();
  for (int o = 128; o; o >>= 1) { if (t < o) red[t] += red[t + o]; __syncthreads(); }
  float inv = 1.f / red[0];
#pragma unroll
  for (int i = 0; i < 16; i++) p[t + i * 256] = vals[i] * inv;
}

// ---------- K3d: ctx[b,a] = sum_s w[b,s] * val[b,s,a] ----------
__global__ void ctx_kernel(const unsigned short* __restrict__ X,
                           const float* __restrict__ w,
                           float* __restrict__ ctx) {
  int b = blockIdx.z, half = blockIdx.y, chunk = blockIdx.x;
  int col = half * 256 + threadIdx.x;
  int s0 = chunk * 256;
  const float* wp = w + b * S_ + s0;
  size_t base = ((size_t)b * S_ + s0) * A6_ + 2 * A_ + col;
  float sum = 0.f;
  for (int s = 0; s < 256; s++) sum += wp[s] * bf1(X[base + (size_t)s * A6_]);
  atomicAdd(&ctx[b * A_ + col], sum);
}

// ---------- K4: final = (ctx + segmax)*out + local_max ----------
__global__ void final_kernel(const unsigned short* __restrict__ X,
                             const float* __restrict__ ctx,
                             float* __restrict__ out) {
  int b = blockIdx.z, rh = blockIdx.y, seg = blockIdx.x;
  int t = threadIdx.x;
  int c0 = t * 2;

  // pass 1: segment max over the 64 rows of this segment (both halves need it)
  float m0 = -1e30f, m1 = -1e30f;
  size_t segbase = ((size_t)b * S_ + seg * 64) * A6_ + 3 * A_ + c0;
  for (int r = 0; r < 64; r++) {
    unsigned int sv = *(const unsigned int*)&X[segbase + (size_t)r * A6_];
    m0 = fmaxf(m0, bflo(sv));
    m1 = fmaxf(m1, bfhi(sv));
  }
  float2 cx = *(const float2*)&ctx[b * A_ + c0];
  float g0 = cx.x + m0, g1 = cx.y + m1;

  // pass 2: 32 output rows
  for (int rr = 0; rr < 32; rr++) {
    int s = seg * 64 + rh * 32 + rr;
    size_t rowb = ((size_t)b * S_ + s) * A6_;
    unsigned int ov = *(const unsigned int*)&X[rowb + 5 * A_ + c0];
    float o0 = bflo(ov), o1 = bfhi(ov);
    float l0 = -INFINITY, l1 = -INFINITY;
#pragma unroll
    for (int d = -2; d <= 2; d++) {
      int sw = s + d;
      if ((unsigned)sw < (unsigned)S_) {
        unsigned int lv = *(const unsigned int*)&X[((size_t)b * S_ + sw) * A6_ + 4 * A_ + c0];
        l0 = fmaxf(l0, bflo(lv));
        l1 = fmaxf(l1, bfhi(lv));
      }
    }
    float2 res;
    res.x = g0 * o0 + l0;
    res.y = g1 * o1 + l1;
    *(float2*)&out[((size_t)b * S_ + s) * A_ + c0] = res;
  }
}

// ---------- launch ----------
extern "C" void kernel_launch(void* const* d_in, const int* in_sizes, int n_in,
                              void* d_out, int out_size, void* d_ws, size_t ws_size,
                              hipStream_t stream) {
  const float* inp  = (const float*)d_in[0];
  const float* W    = (const float*)d_in[1];
  const float* bias = (const float*)d_in[2];
  float* out = (float*)d_out;
  char* ws = (char*)d_ws;

  const size_t X_OFF   = 0;                          // bf16 x: 16384*3072*2 = 100,663,296
  const size_t INP_OFF = 100663296;                  // bf16 inp: 33,554,432
  const size_t W_OFF   = 134217728;                  // bf16 W: 6,291,456
  const size_t AGG_OFF = 140509184;                  // f32 agg: 8192
  const size_t CTX_OFF = AGG_OFF + 8192;             // f32 ctx: 8192
  const size_t SC_OFF  = AGG_OFF + 16384;            // f32 scores/w: 65,536

  __hip_bfloat16* xbf    = (__hip_bfloat16*)(ws + X_OFF);
  __hip_bfloat16* inp_bf = (__hip_bfloat16*)(ws + INP_OFF);
  __hip_bfloat16* w_bf   = (__hip_bfloat16*)(ws + W_OFF);
  float* agg    = (float*)(ws + AGG_OFF);
  float* ctx    = (float*)(ws + CTX_OFF);
  float* scores = (float*)(ws + SC_OFF);

  convert_kernel<<<2048, 256, 0, stream>>>(inp, W, inp_bf, w_bf);
  gemm_kernel<<<3072, 256, 0, stream>>>(inp_bf, w_bf, bias, xbf);
  hipMemsetAsync(ws + AGG_OFF, 0, 16384, stream);  // zero agg + ctx
  agg_kernel<<<dim3(16, 2, 4), 256, 0, stream>>>((const unsigned short*)xbf, agg);
  scores_kernel<<<4096, 256, 0, stream>>>((const unsigned short*)xbf, agg, scores);
  softmax_kernel<<<4, 256, 0, stream>>>(scores);
  ctx_kernel<<<dim3(16, 2, 4), 256, 0, stream>>>((const unsigned short*)xbf, scores, ctx);
  final_kernel<<<dim3(64, 2, 4), 256, 0, stream>>>((const unsigned short*)xbf, ctx, out);
}

// Round 2
// 219.894 us; speedup vs baseline: 1.1156x; 1.1156x over previous
//
#include <hip/hip_runtime.h>
#include <hip/hip_bf16.h>
#include <stdint.h>

#define B_    4
#define S_    4096
#define F_    1024
#define A_    512
#define A6_   3072
#define N3_   1536    // GEMM output cols (seg, loc, out)
#define M_    16384   // B*S

typedef __attribute__((ext_vector_type(8))) __bf16 bf16x8;
typedef __attribute__((ext_vector_type(4))) float  f32x4;

// ---------- helpers ----------
__device__ __forceinline__ float bflo(unsigned int u) {
  union { unsigned int i; float f; } v; v.i = u << 16; return v.f;
}
__device__ __forceinline__ float bfhi(unsigned int u) {
  union { unsigned int i; float f; } v; v.i = u & 0xffff0000u; return v.f;
}

__device__ __forceinline__ ushort4 cvt_bf4(float4 v) {
  ushort4 o;
  o.x = __builtin_bit_cast(unsigned short, __float2bfloat16(v.x));
  o.y = __builtin_bit_cast(unsigned short, __float2bfloat16(v.y));
  o.z = __builtin_bit_cast(unsigned short, __float2bfloat16(v.z));
  o.w = __builtin_bit_cast(unsigned short, __float2bfloat16(v.w));
  return o;
}

typedef __attribute__((address_space(3))) unsigned int lds_uint;
typedef const __attribute__((address_space(1))) unsigned int glob_uint;
__device__ __forceinline__ void lds_load16(const void* g, void* l) {
  __builtin_amdgcn_global_load_lds((glob_uint*)g, (lds_uint*)l, 16, 0, 0);
}

// ---------- K1: convert inp -> bf16 (+ per-(b,f) column sums for mean), W[1536:3072] -> bf16 ----------
__global__ __launch_bounds__(256) void convert_mean_kernel(
    const float* __restrict__ inp, const float* __restrict__ W,
    unsigned short* __restrict__ inp_bf, unsigned short* __restrict__ w_bf,
    float* __restrict__ mu) {
  int blk = blockIdx.x;   // 512
  int t   = threadIdx.x;  // 256
  int r0  = blk * 32;     // 32 rows per block
  int b   = r0 >> 12;
  float acc0 = 0.f, acc1 = 0.f, acc2 = 0.f, acc3 = 0.f;
  for (int r = 0; r < 32; r++) {
    size_t row = (size_t)(r0 + r);
    float4 v = ((const float4*)(inp + row * F_))[t];
    acc0 += v.x; acc1 += v.y; acc2 += v.z; acc3 += v.w;
    ((ushort4*)(inp_bf + row * F_))[t] = cvt_bf4(v);
  }
  atomicAdd(&mu[b * F_ + t * 4 + 0], acc0);
  atomicAdd(&mu[b * F_ + t * 4 + 1], acc1);
  atomicAdd(&mu[b * F_ + t * 4 + 2], acc2);
  atomicAdd(&mu[b * F_ + t * 4 + 3], acc3);

  // W rows 1536..3071 -> bf16 (grid-stride)
  const float* Wc = W + (size_t)N3_ * F_;
  const int n4 = (N3_ * F_) / 4;  // 393216
  for (int i = blk * 256 + t; i < n4; i += 512 * 256) {
    ((ushort4*)w_bf)[i] = cvt_bf4(((const float4*)Wc)[i]);
  }
}

// ---------- K2: agg[b,a] = (mu[b,:]/S) . Wq[a,:] + b_q[a]  (one wave per output) ----------
__global__ void agg_kernel(const float* __restrict__ mu, const float* __restrict__ W,
                           const float* __restrict__ bias, float* __restrict__ agg) {
  int gw = blockIdx.x * 4 + (threadIdx.x >> 6);  // 0..2047
  int lane = threadIdx.x & 63;
  int b = gw >> 9, a = gw & 511;
  const float4* wr = (const float4*)(W + (size_t)a * F_);
  const float4* mr = (const float4*)(mu + b * F_);
  float s = 0.f;
#pragma unroll
  for (int k = 0; k < 4; k++) {
    float4 wv = wr[lane + 64 * k], mv = mr[lane + 64 * k];
    s += wv.x * mv.x + wv.y * mv.y + wv.z * mv.z + wv.w * mv.w;
  }
  for (int off = 32; off; off >>= 1) s += __shfl_down(s, off);
  if (lane == 0) agg[b * A_ + a] = s * (1.f / S_) + bias[a];
}

// ---------- K3: v[b,f] = sum_a agg[b,a] * Wk[a,f];  c[b] = agg[b,:] . b_k ----------
__global__ void v_kernel(const float* __restrict__ agg, const float* __restrict__ W,
                         const float* __restrict__ bias, float* __restrict__ v,
                         float* __restrict__ cvec) {
  int t = threadIdx.x, fc = blockIdx.x;  // 4 blocks x 256
  int f = fc * 256 + t;
  const float* Wk = W + (size_t)A_ * F_;
  float s0 = 0.f, s1 = 0.f, s2 = 0.f, s3 = 0.f;
  for (int a = 0; a < A_; a++) {
    float wv = Wk[(size_t)a * F_ + f];
    s0 += agg[a] * wv;
    s1 += agg[A_ + a] * wv;
    s2 += agg[2 * A_ + a] * wv;
    s3 += agg[3 * A_ + a] * wv;
  }
  v[f] = s0; v[F_ + f] = s1; v[2 * F_ + f] = s2; v[3 * F_ + f] = s3;
  if (fc == 0 && t < 4) {
    float c = 0.f;
    for (int a = 0; a < A_; a++) c += agg[t * A_ + a] * bias[A_ + a];
    cvec[t] = c;
  }
}

// ---------- K4: scores[b,s] = v[b,:] . inp[b,s,:] + c[b]  (one wave per row, f32) ----------
__global__ void scores_kernel(const float* __restrict__ inp, const float* __restrict__ v,
                              const float* __restrict__ cvec, float* __restrict__ scores) {
  int lane = threadIdx.x & 63;
  int row = blockIdx.x * 4 + (threadIdx.x >> 6);  // [0, 16384)
  int b = row >> 12;
  const float4* ip = (const float4*)(inp + (size_t)row * F_);
  const float4* vp = (const float4*)(v + b * F_);
  float s = 0.f;
#pragma unroll
  for (int k = 0; k < 4; k++) {
    float4 a = ip[lane + 64 * k], c = vp[lane + 64 * k];
    s += a.x * c.x + a.y * c.y + a.z * c.z + a.w * c.w;
  }
  for (int off = 32; off; off >>= 1) s += __shfl_down(s, off);
  if (lane == 0) scores[row] = s + cvec[b];
}

// ---------- K5: softmax over s (per b), in place ----------
__global__ void softmax_kernel(float* __restrict__ sc) {
  __shared__ float red[256];
  int b = blockIdx.x, t = threadIdx.x;
  float* p = sc + b * S_;
  float vals[16];
  float m = -1e30f;
#pragma unroll
  for (int i = 0; i < 16; i++) { vals[i] = p[t + i * 256]; m = fmaxf(m, vals[i]); }
  red[t] = m; __syncthreads();
  for (int o = 128; o; o >>= 1) { if (t < o) red[t] = fmaxf(red[t], red[t + o]); __syncthreads(); }
  m = red[0]; __syncthreads();
  float sum = 0.f;
#pragma unroll
  for (int i = 0; i < 16; i++) { vals[i] = __expf(vals[i] - m); sum += vals[i]; }
  red[t] = sum; __syncthreads();
  for (int o = 128; o; o >>= 1) { if (t < o) red[t] += red[t + o]; __syncthreads(); }
  float inv = 1.f / red[0];
#pragma unroll
  for (int i = 0; i < 16; i++) p[t + i * 256] = vals[i] * inv;
}

// ---------- K6: u[b,f] = sum_s w[b,s] * inp[b,s,f] ----------
__global__ void u_kernel(const float* __restrict__ inp, const float* __restrict__ w,
                         float* __restrict__ u) {
  int b = blockIdx.z, fc = blockIdx.y, sc = blockIdx.x;  // 16 x 4 x 4
  int t = threadIdx.x;
  int f = fc * 256 + t;
  int s0 = sc * 256;
  const float* wp = w + b * S_ + s0;
  const float* ip = inp + ((size_t)(b * S_ + s0)) * F_ + f;
  float acc = 0.f;
  for (int s = 0; s < 256; s++) acc += wp[s] * ip[(size_t)s * F_];
  atomicAdd(&u[b * F_ + f], acc);
}

// ---------- K7: ctx[b,a] = u[b,:] . Wv[a,:] + b_v[a]  (one wave per output) ----------
__global__ void ctx_kernel(const float* __restrict__ u, const float* __restrict__ W,
                           const float* __restrict__ bias, float* __restrict__ ctx) {
  int gw = blockIdx.x * 4 + (threadIdx.x >> 6);
  int lane = threadIdx.x & 63;
  int b = gw >> 9, a = gw & 511;
  const float4* wr = (const float4*)(W + (size_t)(2 * A_ + a) * F_);
  const float4* ur = (const float4*)(u + b * F_);
  float s = 0.f;
#pragma unroll
  for (int k = 0; k < 4; k++) {
    float4 wv = wr[lane + 64 * k], uv = ur[lane + 64 * k];
    s += wv.x * uv.x + wv.y * uv.y + wv.z * uv.z + wv.w * uv.w;
  }
  for (int off = 32; off; off >>= 1) s += __shfl_down(s, off);
  if (lane == 0) ctx[b * A_ + a] = s + bias[2 * A_ + a];
}

// ---------- K8: bf16 GEMM  X[M,1536] = A[M,1024] @ Wslo[1536,1024]^T + b_slo ----------
__global__ __launch_bounds__(256) void gemm_kernel(
    const __hip_bfloat16* __restrict__ Abf,
    const __hip_bfloat16* __restrict__ Wbf,
    const float* __restrict__ bias,
    __hip_bfloat16* __restrict__ X) {
  __shared__ unsigned short ldsA[128 * 32];
  __shared__ unsigned short ldsB[128 * 32];

  int bid = blockIdx.x;
  // XCD-aware swizzle: 1536 blocks, 1536/8 = 192
  int swz = (bid & 7) * 192 + (bid >> 3);
  const int NBLK = N3_ / 128;  // 12
  int mb = swz / NBLK;
  int nb = swz % NBLK;

  int tid  = threadIdx.x;
  int lane = tid & 63;
  int wv   = tid >> 6;
  int wm   = wv >> 1;
  int wn   = wv & 1;

  f32x4 acc[4][4];
#pragma unroll
  for (int i = 0; i < 4; i++)
#pragma unroll
    for (int j = 0; j < 4; j++) acc[i][j] = (f32x4){0.f, 0.f, 0.f, 0.f};

  int p0 = wv * 128 + lane;
  int r0 = p0 >> 2, ks0 = p0 & 3;
  int p1 = p0 + 64;
  int r1 = p1 >> 2, ks1 = p1 & 3;

  const __hip_bfloat16* Ab = Abf + (size_t)mb * 128 * F_;
  const __hip_bfloat16* Bb = Wbf + (size_t)nb * 128 * F_;

  for (int kt = 0; kt < F_ / 32; ++kt) {
    int kof = kt * 32;
    lds_load16(Ab + (size_t)r0 * F_ + kof + ks0 * 8, &ldsA[(wv * 128) * 8]);
    lds_load16(Ab + (size_t)r1 * F_ + kof + ks1 * 8, &ldsA[(wv * 128 + 64) * 8]);
    lds_load16(Bb + (size_t)r0 * F_ + kof + ks0 * 8, &ldsB[(wv * 128) * 8]);
    lds_load16(Bb + (size_t)r1 * F_ + kof + ks1 * 8, &ldsB[(wv * 128 + 64) * 8]);
    __syncthreads();

    bf16x8 af[4], bfr[4];
#pragma unroll
    for (int i = 0; i < 4; i++) {
      af[i]  = *(const bf16x8*)&ldsA[(wm * 64 + i * 16 + (lane & 15)) * 32 + (lane >> 4) * 8];
      bfr[i] = *(const bf16x8*)&ldsB[(wn * 64 + i * 16 + (lane & 15)) * 32 + (lane >> 4) * 8];
    }
#pragma unroll
    for (int i = 0; i < 4; i++)
#pragma unroll
      for (int j = 0; j < 4; j++)
        acc[i][j] = __builtin_amdgcn_mfma_f32_16x16x32_bf16(af[i], bfr[j], acc[i][j], 0, 0, 0);
    __syncthreads();
  }

#pragma unroll
  for (int i = 0; i < 4; i++) {
    int grow_base = mb * 128 + wm * 64 + i * 16 + (lane >> 4) * 4;
#pragma unroll
    for (int j = 0; j < 4; j++) {
      int gcol = nb * 128 + wn * 64 + j * 16 + (lane & 15);
      float bv = bias[gcol];
#pragma unroll
      for (int rg = 0; rg < 4; rg++) {
        int grow = grow_base + rg;
        X[(size_t)grow * N3_ + gcol] = __float2bfloat16(acc[i][j][rg] + bv);
      }
    }
  }
}

// ---------- K9: final = (ctx + segmax)*out + local_max ----------
__global__ void final_kernel(const unsigned short* __restrict__ X,
                             const float* __restrict__ ctx,
                             float* __restrict__ out) {
  int b = blockIdx.z, rh = blockIdx.y, seg = blockIdx.x;
  int t = threadIdx.x;
  int c0 = t * 2;

  float m0 = -1e30f, m1 = -1e30f;
  size_t segbase = ((size_t)b * S_ + seg * 64) * N3_ + c0;  // seg chunk at col 0
  for (int r = 0; r < 64; r++) {
    unsigned int sv = *(const unsigned int*)&X[segbase + (size_t)r * N3_];
    m0 = fmaxf(m0, bflo(sv));
    m1 = fmaxf(m1, bfhi(sv));
  }
  float2 cx = *(const float2*)&ctx[b * A_ + c0];
  float g0 = cx.x + m0, g1 = cx.y + m1;

  for (int rr = 0; rr < 32; rr++) {
    int s = seg * 64 + rh * 32 + rr;
    size_t rowb = ((size_t)b * S_ + s) * N3_;
    unsigned int ov = *(const unsigned int*)&X[rowb + 2 * A_ + c0];  // out chunk
    float o0 = bflo(ov), o1 = bfhi(ov);
    float l0 = -INFINITY, l1 = -INFINITY;
#pragma unroll
    for (int d = -2; d <= 2; d++) {
      int sw = s + d;
      if ((unsigned)sw < (unsigned)S_) {
        unsigned int lv = *(const unsigned int*)&X[((size_t)b * S_ + sw) * N3_ + A_ + c0];  // loc chunk
        l0 = fmaxf(l0, bflo(lv));
        l1 = fmaxf(l1, bfhi(lv));
      }
    }
    float2 res;
    res.x = g0 * o0 + l0;
    res.y = g1 * o1 + l1;
    *(float2*)&out[((size_t)b * S_ + s) * A_ + c0] = res;
  }
}

// ---------- launch ----------
extern "C" void kernel_launch(void* const* d_in, const int* in_sizes, int n_in,
                              void* d_out, int out_size, void* d_ws, size_t ws_size,
                              hipStream_t stream) {
  const float* inp  = (const float*)d_in[0];
  const float* W    = (const float*)d_in[1];
  const float* bias = (const float*)d_in[2];
  float* out = (float*)d_out;
  char* ws = (char*)d_ws;

  const size_t X_OFF    = 0;                        // bf16 X: 16384*1536*2 = 50,331,648
  const size_t INP_OFF  = 50331648;                 // bf16 inp: 33,554,432
  const size_t W_OFF    = 83886080;                 // bf16 W[1536:3072]: 3,145,728
  const size_t MU_OFF   = 87031808;                 // f32 mu sums: 16,384
  const size_t U_OFF    = MU_OFF + 16384;           // f32 u: 16,384
  const size_t AGG_OFF  = MU_OFF + 32768;           // f32 agg: 8,192
  const size_t V_OFF    = AGG_OFF + 8192;           // f32 v: 16,384
  const size_t CV_OFF   = V_OFF + 16384;            // f32 c: 256
  const size_t CTX_OFF  = CV_OFF + 256;             // f32 ctx: 8,192
  const size_t SC_OFF   = CTX_OFF + 8192;           // f32 scores: 65,536

  unsigned short* xbf    = (unsigned short*)(ws + X_OFF);
  unsigned short* inp_bf = (unsigned short*)(ws + INP_OFF);
  unsigned short* w_bf   = (unsigned short*)(ws + W_OFF);
  float* mu     = (float*)(ws + MU_OFF);
  float* u      = (float*)(ws + U_OFF);
  float* agg    = (float*)(ws + AGG_OFF);
  float* v      = (float*)(ws + V_OFF);
  float* cvec   = (float*)(ws + CV_OFF);
  float* ctx    = (float*)(ws + CTX_OFF);
  float* scores = (float*)(ws + SC_OFF);

  hipMemsetAsync(ws + MU_OFF, 0, 32768, stream);  // zero mu + u
  convert_mean_kernel<<<512, 256, 0, stream>>>(inp, W, inp_bf, w_bf, mu);
  gemm_kernel<<<1536, 256, 0, stream>>>((const __hip_bfloat16*)inp_bf,
                                        (const __hip_bfloat16*)w_bf,
                                        bias + 3 * A_, (__hip_bfloat16*)xbf);
  agg_kernel<<<512, 256, 0, stream>>>(mu, W, bias, agg);
  v_kernel<<<4, 256, 0, stream>>>(agg, W, bias, v, cvec);
  scores_kernel<<<4096, 256, 0, stream>>>(inp, v, cvec, scores);
  softmax_kernel<<<4, 256, 0, stream>>>(scores);
  u_kernel<<<dim3(16, 4, 4), 256, 0, stream>>>(inp, scores, u);
  ctx_kernel<<<512, 256, 0, stream>>>(u, W, bias, ctx);
  final_kernel<<<dim3(64, 2, 4), 256, 0, stream>>>(xbf, ctx, out);
}

// Round 3
// 159.728 us; speedup vs baseline: 1.5358x; 1.3767x over previous
//
#include <hip/hip_runtime.h>
#include <hip/hip_bf16.h>
#include <stdint.h>

#define B_    4
#define S_    4096
#define F_    1024
#define A_    512
#define N3_   1536    // GEMM output cols (seg, loc, out)
#define M_    16384   // B*S

typedef __attribute__((ext_vector_type(8))) __bf16 bf16x8;
typedef __attribute__((ext_vector_type(4))) float  f32x4;

// ---------- helpers ----------
__device__ __forceinline__ float bflo(unsigned int u) {
  union { unsigned int i; float f; } v; v.i = u << 16; return v.f;
}
__device__ __forceinline__ float bfhi(unsigned int u) {
  union { unsigned int i; float f; } v; v.i = u & 0xffff0000u; return v.f;
}

__device__ __forceinline__ ushort4 cvt_bf4(float4 v) {
  ushort4 o;
  o.x = __builtin_bit_cast(unsigned short, __float2bfloat16(v.x));
  o.y = __builtin_bit_cast(unsigned short, __float2bfloat16(v.y));
  o.z = __builtin_bit_cast(unsigned short, __float2bfloat16(v.z));
  o.w = __builtin_bit_cast(unsigned short, __float2bfloat16(v.w));
  return o;
}

typedef __attribute__((address_space(3))) unsigned int lds_uint;
typedef const __attribute__((address_space(1))) unsigned int glob_uint;
__device__ __forceinline__ void lds_load16(const void* g, void* l) {
  __builtin_amdgcn_global_load_lds((glob_uint*)g, (lds_uint*)l, 16, 0, 0);
}

// ---------- K1: convert inp -> bf16 (+ per-(b,f) column sums for mean), W[1536:3072] -> bf16 ----------
__global__ __launch_bounds__(256) void convert_mean_kernel(
    const float* __restrict__ inp, const float* __restrict__ W,
    unsigned short* __restrict__ inp_bf, unsigned short* __restrict__ w_bf,
    float* __restrict__ mu) {
  int blk = blockIdx.x;   // 512
  int t   = threadIdx.x;  // 256
  int r0  = blk * 32;     // 32 rows per block
  int b   = r0 >> 12;
  float acc0 = 0.f, acc1 = 0.f, acc2 = 0.f, acc3 = 0.f;
  for (int r = 0; r < 32; r++) {
    size_t row = (size_t)(r0 + r);
    float4 v = ((const float4*)(inp + row * F_))[t];
    acc0 += v.x; acc1 += v.y; acc2 += v.z; acc3 += v.w;
    ((ushort4*)(inp_bf + row * F_))[t] = cvt_bf4(v);
  }
  atomicAdd(&mu[b * F_ + t * 4 + 0], acc0);
  atomicAdd(&mu[b * F_ + t * 4 + 1], acc1);
  atomicAdd(&mu[b * F_ + t * 4 + 2], acc2);
  atomicAdd(&mu[b * F_ + t * 4 + 3], acc3);

  // W rows 1536..3071 -> bf16 (grid-stride)
  const float* Wc = W + (size_t)N3_ * F_;
  const int n4 = (N3_ * F_) / 4;  // 393216
  for (int i = blk * 256 + t; i < n4; i += 512 * 256) {
    ((ushort4*)w_bf)[i] = cvt_bf4(((const float4*)Wc)[i]);
  }
}

// ---------- K2: agg[b,a] = (mu[b,:]/S) . Wq[a,:] + b_q[a]  (one wave per output) ----------
__global__ void agg_kernel(const float* __restrict__ mu, const float* __restrict__ W,
                           const float* __restrict__ bias, float* __restrict__ agg) {
  int gw = blockIdx.x * 4 + (threadIdx.x >> 6);  // 0..2047
  int lane = threadIdx.x & 63;
  int b = gw >> 9, a = gw & 511;
  const float4* wr = (const float4*)(W + (size_t)a * F_);
  const float4* mr = (const float4*)(mu + b * F_);
  float s = 0.f;
#pragma unroll
  for (int k = 0; k < 4; k++) {
    float4 wv = wr[lane + 64 * k], mv = mr[lane + 64 * k];
    s += wv.x * mv.x + wv.y * mv.y + wv.z * mv.z + wv.w * mv.w;
  }
  for (int off = 32; off; off >>= 1) s += __shfl_down(s, off);
  if (lane == 0) agg[b * A_ + a] = s * (1.f / S_) + bias[a];
}

// ---------- K3: v[b,f] += sum_{a in chunk} agg[b,a]*Wk[a,f];  cvec[b] = agg[b,:].b_k ----------
__global__ void v_kernel(const float* __restrict__ agg, const float* __restrict__ W,
                         const float* __restrict__ bias, float* __restrict__ v,
                         float* __restrict__ cvec) {
  int fc = blockIdx.x;  // 0..3
  int ac = blockIdx.y;  // 0..7
  int t = threadIdx.x;
  int f = fc * 256 + t;
  const float* Wk = W + (size_t)A_ * F_;
  float s0 = 0.f, s1 = 0.f, s2 = 0.f, s3 = 0.f;
  int a0 = ac * 64;
  for (int a = a0; a < a0 + 64; a++) {
    float wv = Wk[(size_t)a * F_ + f];
    s0 += agg[a] * wv;
    s1 += agg[A_ + a] * wv;
    s2 += agg[2 * A_ + a] * wv;
    s3 += agg[3 * A_ + a] * wv;
  }
  atomicAdd(&v[f], s0);
  atomicAdd(&v[F_ + f], s1);
  atomicAdd(&v[2 * F_ + f], s2);
  atomicAdd(&v[3 * F_ + f], s3);

  if (fc == 0 && ac == 0) {  // cvec, wave-parallel: 4 waves, one per b
    int bb = t >> 6, l = t & 63;
    float c = 0.f;
#pragma unroll
    for (int i = 0; i < 8; i++) c += agg[bb * A_ + l + 64 * i] * bias[A_ + l + 64 * i];
    for (int off = 32; off; off >>= 1) c += __shfl_down(c, off);
    if (l == 0) cvec[bb] = c;
  }
}

// ---------- K4: scores[b,s] = v[b,:] . inp_bf[b,s,:] + c[b]  (one wave per row) ----------
__global__ void scores_kernel(const unsigned short* __restrict__ inp_bf,
                              const float* __restrict__ v,
                              const float* __restrict__ cvec, float* __restrict__ scores) {
  int lane = threadIdx.x & 63;
  int row = blockIdx.x * 4 + (threadIdx.x >> 6);  // [0, 16384)
  int b = row >> 12;
  const uint4* ip = (const uint4*)(inp_bf + (size_t)row * F_);  // 128 uint4/row
  const float4* vp = (const float4*)(v + b * F_);
  float s = 0.f;
#pragma unroll
  for (int k = 0; k < 2; k++) {
    uint4 x = ip[lane + 64 * k];
    float4 va = vp[(lane + 64 * k) * 2];
    float4 vb = vp[(lane + 64 * k) * 2 + 1];
    s += bflo(x.x) * va.x + bfhi(x.x) * va.y + bflo(x.y) * va.z + bfhi(x.y) * va.w +
         bflo(x.z) * vb.x + bfhi(x.z) * vb.y + bflo(x.w) * vb.z + bfhi(x.w) * vb.w;
  }
  for (int off = 32; off; off >>= 1) s += __shfl_down(s, off);
  if (lane == 0) scores[row] = s + cvec[b];
}

// ---------- K5: softmax over s (per b), in place ----------
__global__ void softmax_kernel(float* __restrict__ sc) {
  __shared__ float red[256];
  int b = blockIdx.x, t = threadIdx.x;
  float* p = sc + b * S_;
  float vals[16];
  float m = -1e30f;
#pragma unroll
  for (int i = 0; i < 16; i++) { vals[i] = p[t + i * 256]; m = fmaxf(m, vals[i]); }
  red[t] = m; __syncthreads();
  for (int o = 128; o; o >>= 1) { if (t < o) red[t] = fmaxf(red[t], red[t + o]); __syncthreads(); }
  m = red[0]; __syncthreads();
  float sum = 0.f;
#pragma unroll
  for (int i = 0; i < 16; i++) { vals[i] = __expf(vals[i] - m); sum += vals[i]; }
  red[t] = sum; __syncthreads();
  for (int o = 128; o; o >>= 1) { if (t < o) red[t] += red[t + o]; __syncthreads(); }
  float inv = 1.f / red[0];
#pragma unroll
  for (int i = 0; i < 16; i++) p[t + i * 256] = vals[i] * inv;
}

// ---------- K6: u[b,f] = sum_s w[b,s] * inp_bf[b,s,f] ----------
__global__ void u_kernel(const unsigned short* __restrict__ inp_bf,
                         const float* __restrict__ w, float* __restrict__ u) {
  int b = blockIdx.z, fc = blockIdx.y, sc = blockIdx.x;  // 32 x 2 x 4
  int t = threadIdx.x;
  int f2 = fc * 512 + t * 2;
  int s0 = sc * 128;
  const float* wp = w + b * S_ + s0;
  const unsigned short* ip = inp_bf + ((size_t)(b * S_ + s0)) * F_ + f2;
  float a0 = 0.f, a1 = 0.f;
  for (int s = 0; s < 128; s++) {
    unsigned int xv = *(const unsigned int*)&ip[(size_t)s * F_];
    float ws = wp[s];
    a0 += ws * bflo(xv);
    a1 += ws * bfhi(xv);
  }
  atomicAdd(&u[b * F_ + f2], a0);
  atomicAdd(&u[b * F_ + f2 + 1], a1);
}

// ---------- K7: ctx[b,a] = u[b,:] . Wv[a,:] + b_v[a]  (one wave per output) ----------
__global__ void ctx_kernel(const float* __restrict__ u, const float* __restrict__ W,
                           const float* __restrict__ bias, float* __restrict__ ctx) {
  int gw = blockIdx.x * 4 + (threadIdx.x >> 6);
  int lane = threadIdx.x & 63;
  int b = gw >> 9, a = gw & 511;
  const float4* wr = (const float4*)(W + (size_t)(2 * A_ + a) * F_);
  const float4* ur = (const float4*)(u + b * F_);
  float s = 0.f;
#pragma unroll
  for (int k = 0; k < 4; k++) {
    float4 wv = wr[lane + 64 * k], uv = ur[lane + 64 * k];
    s += wv.x * uv.x + wv.y * uv.y + wv.z * uv.z + wv.w * uv.w;
  }
  for (int off = 32; off; off >>= 1) s += __shfl_down(s, off);
  if (lane == 0) ctx[b * A_ + a] = s + bias[2 * A_ + a];
}

// ---------- K8: bf16 GEMM  X[M,1536] = A[M,1024] @ Wslo[1536,1024]^T + b_slo ----------
__global__ __launch_bounds__(256) void gemm_kernel(
    const __hip_bfloat16* __restrict__ Abf,
    const __hip_bfloat16* __restrict__ Wbf,
    const float* __restrict__ bias,
    __hip_bfloat16* __restrict__ X) {
  __shared__ unsigned short ldsA[128 * 32];
  __shared__ unsigned short ldsB[128 * 32];

  int bid = blockIdx.x;
  int swz = (bid & 7) * 192 + (bid >> 3);
  const int NBLK = N3_ / 128;  // 12
  int mb = swz / NBLK;
  int nb = swz % NBLK;

  int tid  = threadIdx.x;
  int lane = tid & 63;
  int wv   = tid >> 6;
  int wm   = wv >> 1;
  int wn   = wv & 1;

  f32x4 acc[4][4];
#pragma unroll
  for (int i = 0; i < 4; i++)
#pragma unroll
    for (int j = 0; j < 4; j++) acc[i][j] = (f32x4){0.f, 0.f, 0.f, 0.f};

  int p0 = wv * 128 + lane;
  int r0 = p0 >> 2, ks0 = p0 & 3;
  int p1 = p0 + 64;
  int r1 = p1 >> 2, ks1 = p1 & 3;

  const __hip_bfloat16* Ab = Abf + (size_t)mb * 128 * F_;
  const __hip_bfloat16* Bb = Wbf + (size_t)nb * 128 * F_;

  for (int kt = 0; kt < F_ / 32; ++kt) {
    int kof = kt * 32;
    lds_load16(Ab + (size_t)r0 * F_ + kof + ks0 * 8, &ldsA[(wv * 128) * 8]);
    lds_load16(Ab + (size_t)r1 * F_ + kof + ks1 * 8, &ldsA[(wv * 128 + 64) * 8]);
    lds_load16(Bb + (size_t)r0 * F_ + kof + ks0 * 8, &ldsB[(wv * 128) * 8]);
    lds_load16(Bb + (size_t)r1 * F_ + kof + ks1 * 8, &ldsB[(wv * 128 + 64) * 8]);
    __syncthreads();

    bf16x8 af[4], bfr[4];
#pragma unroll
    for (int i = 0; i < 4; i++) {
      af[i]  = *(const bf16x8*)&ldsA[(wm * 64 + i * 16 + (lane & 15)) * 32 + (lane >> 4) * 8];
      bfr[i] = *(const bf16x8*)&ldsB[(wn * 64 + i * 16 + (lane & 15)) * 32 + (lane >> 4) * 8];
    }
#pragma unroll
    for (int i = 0; i < 4; i++)
#pragma unroll
      for (int j = 0; j < 4; j++)
        acc[i][j] = __builtin_amdgcn_mfma_f32_16x16x32_bf16(af[i], bfr[j], acc[i][j], 0, 0, 0);
    __syncthreads();
  }

#pragma unroll
  for (int i = 0; i < 4; i++) {
    int grow_base = mb * 128 + wm * 64 + i * 16 + (lane >> 4) * 4;
#pragma unroll
    for (int j = 0; j < 4; j++) {
      int gcol = nb * 128 + wn * 64 + j * 16 + (lane & 15);
      float bv = bias[gcol];
#pragma unroll
      for (int rg = 0; rg < 4; rg++) {
        int grow = grow_base + rg;
        X[(size_t)grow * N3_ + gcol] = __float2bfloat16(acc[i][j][rg] + bv);
      }
    }
  }
}

// ---------- K9: final = (ctx + segmax)*out + local_max  (one block per 64-row segment) ----------
__global__ void final_kernel(const unsigned short* __restrict__ X,
                             const float* __restrict__ ctx,
                             float* __restrict__ out) {
  int b = blockIdx.y, seg = blockIdx.x;  // 4, 64
  int t = threadIdx.x;
  int c0 = t * 2;
  int sbase = seg * 64;

  // segment max over all 64 rows
  float m0 = -1e30f, m1 = -1e30f;
  size_t base = ((size_t)b * S_ + sbase) * N3_;
  for (int r = 0; r < 64; r++) {
    unsigned int sv = *(const unsigned int*)&X[base + (size_t)r * N3_ + c0];
    m0 = fmaxf(m0, bflo(sv));
    m1 = fmaxf(m1, bfhi(sv));
  }
  float2 cx = *(const float2*)&ctx[b * A_ + c0];
  float g0 = cx.x + m0, g1 = cx.y + m1;

  // rolling 5-row window for loc; 0xFF80 = bf16 -inf
  auto loadloc = [&](int s) -> unsigned int {
    if ((unsigned)s >= (unsigned)S_) return 0xFF80FF80u;
    return *(const unsigned int*)&X[((size_t)b * S_ + s) * N3_ + A_ + c0];
  };
  unsigned int w0 = loadloc(sbase - 2), w1 = loadloc(sbase - 1);
  unsigned int w2 = loadloc(sbase),     w3 = loadloc(sbase + 1);
  for (int rr = 0; rr < 64; rr++) {
    int s = sbase + rr;
    unsigned int w4 = loadloc(s + 2);
    float lo = fmaxf(fmaxf(fmaxf(bflo(w0), bflo(w1)), fmaxf(bflo(w2), bflo(w3))), bflo(w4));
    float hi = fmaxf(fmaxf(fmaxf(bfhi(w0), bfhi(w1)), fmaxf(bfhi(w2), bfhi(w3))), bfhi(w4));
    unsigned int ov = *(const unsigned int*)&X[((size_t)b * S_ + s) * N3_ + 2 * A_ + c0];
    float2 res;
    res.x = g0 * bflo(ov) + lo;
    res.y = g1 * bfhi(ov) + hi;
    *(float2*)&out[((size_t)b * S_ + s) * A_ + c0] = res;
    w0 = w1; w1 = w2; w2 = w3; w3 = w4;
  }
}

// ---------- launch ----------
extern "C" void kernel_launch(void* const* d_in, const int* in_sizes, int n_in,
                              void* d_out, int out_size, void* d_ws, size_t ws_size,
                              hipStream_t stream) {
  const float* inp  = (const float*)d_in[0];
  const float* W    = (const float*)d_in[1];
  const float* bias = (const float*)d_in[2];
  float* out = (float*)d_out;
  char* ws = (char*)d_ws;

  const size_t X_OFF    = 0;                        // bf16 X: 50,331,648
  const size_t INP_OFF  = 50331648;                 // bf16 inp: 33,554,432
  const size_t W_OFF    = 83886080;                 // bf16 W[1536:3072]: 3,145,728
  const size_t MU_OFF   = 87031808;                 // f32 mu: 16,384
  const size_t U_OFF    = MU_OFF + 16384;           // f32 u: 16,384
  const size_t V_OFF    = U_OFF + 16384;            // f32 v: 16,384
  const size_t CV_OFF   = V_OFF + 16384;            // f32 cvec: 256
  const size_t AGG_OFF  = CV_OFF + 256;             // f32 agg: 8,192
  const size_t CTX_OFF  = AGG_OFF + 8192;           // f32 ctx: 8,192
  const size_t SC_OFF   = CTX_OFF + 8192;           // f32 scores: 65,536

  unsigned short* xbf    = (unsigned short*)(ws + X_OFF);
  unsigned short* inp_bf = (unsigned short*)(ws + INP_OFF);
  unsigned short* w_bf   = (unsigned short*)(ws + W_OFF);
  float* mu     = (float*)(ws + MU_OFF);
  float* u      = (float*)(ws + U_OFF);
  float* v      = (float*)(ws + V_OFF);
  float* cvec   = (float*)(ws + CV_OFF);
  float* agg    = (float*)(ws + AGG_OFF);
  float* ctx    = (float*)(ws + CTX_OFF);
  float* scores = (float*)(ws + SC_OFF);

  hipMemsetAsync(ws + MU_OFF, 0, 3 * 16384 + 256, stream);  // zero mu, u, v, cvec
  convert_mean_kernel<<<512, 256, 0, stream>>>(inp, W, inp_bf, w_bf, mu);
  gemm_kernel<<<1536, 256, 0, stream>>>((const __hip_bfloat16*)inp_bf,
                                        (const __hip_bfloat16*)w_bf,
                                        bias + 3 * A_, (__hip_bfloat16*)xbf);
  agg_kernel<<<512, 256, 0, stream>>>(mu, W, bias, agg);
  v_kernel<<<dim3(4, 8), 256, 0, stream>>>(agg, W, bias, v, cvec);
  scores_kernel<<<4096, 256, 0, stream>>>(inp_bf, v, cvec, scores);
  softmax_kernel<<<4, 256, 0, stream>>>(scores);
  u_kernel<<<dim3(32, 2, 4), 256, 0, stream>>>(inp_bf, scores, u);
  ctx_kernel<<<512, 256, 0, stream>>>(u, W, bias, ctx);
  final_kernel<<<dim3(64, 4), 256, 0, stream>>>(xbf, ctx, out);
}

// Round 4
// 151.277 us; speedup vs baseline: 1.6216x; 1.0559x over previous
//
#include <hip/hip_runtime.h>
#include <hip/hip_bf16.h>
#include <stdint.h>

#define B_    4
#define S_    4096
#define F_    1024
#define A_    512
#define N3_   1536    // GEMM output cols (seg, loc, out)
#define M_    16384   // B*S

#define BM    256
#define BN    192
#define BK    64
#define NT    (F_ / BK)   // 16 K-tiles

typedef __attribute__((ext_vector_type(8))) __bf16 bf16x8;
typedef __attribute__((ext_vector_type(4))) float  f32x4;

// ---------- helpers ----------
__device__ __forceinline__ float bflo(unsigned int u) {
  union { unsigned int i; float f; } v; v.i = u << 16; return v.f;
}
__device__ __forceinline__ float bfhi(unsigned int u) {
  union { unsigned int i; float f; } v; v.i = u & 0xffff0000u; return v.f;
}

__device__ __forceinline__ ushort4 cvt_bf4(float4 v) {
  ushort4 o;
  o.x = __builtin_bit_cast(unsigned short, __float2bfloat16(v.x));
  o.y = __builtin_bit_cast(unsigned short, __float2bfloat16(v.y));
  o.z = __builtin_bit_cast(unsigned short, __float2bfloat16(v.z));
  o.w = __builtin_bit_cast(unsigned short, __float2bfloat16(v.w));
  return o;
}

typedef __attribute__((address_space(3))) unsigned int lds_uint;
typedef const __attribute__((address_space(1))) unsigned int glob_uint;
__device__ __forceinline__ void lds_load16(const void* g, void* l) {
  __builtin_amdgcn_global_load_lds((glob_uint*)g, (lds_uint*)l, 16, 0, 0);
}

// ---------- K1: convert inp -> bf16 (+ per-(b,f) column sums for mean), W[1536:3072] -> bf16 ----------
__global__ __launch_bounds__(256) void convert_mean_kernel(
    const float* __restrict__ inp, const float* __restrict__ W,
    unsigned short* __restrict__ inp_bf, unsigned short* __restrict__ w_bf,
    float* __restrict__ mu) {
  int blk = blockIdx.x;   // 512
  int t   = threadIdx.x;  // 256
  int r0  = blk * 32;     // 32 rows per block
  int b   = r0 >> 12;
  float acc0 = 0.f, acc1 = 0.f, acc2 = 0.f, acc3 = 0.f;
  for (int r = 0; r < 32; r++) {
    size_t row = (size_t)(r0 + r);
    float4 v = ((const float4*)(inp + row * F_))[t];
    acc0 += v.x; acc1 += v.y; acc2 += v.z; acc3 += v.w;
    ((ushort4*)(inp_bf + row * F_))[t] = cvt_bf4(v);
  }
  atomicAdd(&mu[b * F_ + t * 4 + 0], acc0);
  atomicAdd(&mu[b * F_ + t * 4 + 1], acc1);
  atomicAdd(&mu[b * F_ + t * 4 + 2], acc2);
  atomicAdd(&mu[b * F_ + t * 4 + 3], acc3);

  const float* Wc = W + (size_t)N3_ * F_;
  const int n4 = (N3_ * F_) / 4;  // 393216
  for (int i = blk * 256 + t; i < n4; i += 512 * 256) {
    ((ushort4*)w_bf)[i] = cvt_bf4(((const float4*)Wc)[i]);
  }
}

// ---------- K2: agg[b,a] = (mu[b,:]/S) . Wq[a,:] + b_q[a] ----------
__global__ void agg_kernel(const float* __restrict__ mu, const float* __restrict__ W,
                           const float* __restrict__ bias, float* __restrict__ agg) {
  int gw = blockIdx.x * 4 + (threadIdx.x >> 6);  // 0..2047
  int lane = threadIdx.x & 63;
  int b = gw >> 9, a = gw & 511;
  const float4* wr = (const float4*)(W + (size_t)a * F_);
  const float4* mr = (const float4*)(mu + b * F_);
  float s = 0.f;
#pragma unroll
  for (int k = 0; k < 4; k++) {
    float4 wv = wr[lane + 64 * k], mv = mr[lane + 64 * k];
    s += wv.x * mv.x + wv.y * mv.y + wv.z * mv.z + wv.w * mv.w;
  }
  for (int off = 32; off; off >>= 1) s += __shfl_down(s, off);
  if (lane == 0) agg[b * A_ + a] = s * (1.f / S_) + bias[a];
}

// ---------- K3: v[b,f] += sum_{a in chunk} agg[b,a]*Wk[a,f];  cvec[b] = agg[b,:].b_k ----------
__global__ void v_kernel(const float* __restrict__ agg, const float* __restrict__ W,
                         const float* __restrict__ bias, float* __restrict__ v,
                         float* __restrict__ cvec) {
  int fc = blockIdx.x;  // 0..3
  int ac = blockIdx.y;  // 0..7
  int t = threadIdx.x;
  int f = fc * 256 + t;
  const float* Wk = W + (size_t)A_ * F_;
  float s0 = 0.f, s1 = 0.f, s2 = 0.f, s3 = 0.f;
  int a0 = ac * 64;
  for (int a = a0; a < a0 + 64; a++) {
    float wv = Wk[(size_t)a * F_ + f];
    s0 += agg[a] * wv;
    s1 += agg[A_ + a] * wv;
    s2 += agg[2 * A_ + a] * wv;
    s3 += agg[3 * A_ + a] * wv;
  }
  atomicAdd(&v[f], s0);
  atomicAdd(&v[F_ + f], s1);
  atomicAdd(&v[2 * F_ + f], s2);
  atomicAdd(&v[3 * F_ + f], s3);

  if (fc == 0 && ac == 0) {
    int bb = t >> 6, l = t & 63;
    float c = 0.f;
#pragma unroll
    for (int i = 0; i < 8; i++) c += agg[bb * A_ + l + 64 * i] * bias[A_ + l + 64 * i];
    for (int off = 32; off; off >>= 1) c += __shfl_down(c, off);
    if (l == 0) cvec[bb] = c;
  }
}

// ---------- K4: scores[b,s] = v[b,:] . inp_bf[b,s,:] + c[b] ----------
__global__ void scores_kernel(const unsigned short* __restrict__ inp_bf,
                              const float* __restrict__ v,
                              const float* __restrict__ cvec, float* __restrict__ scores) {
  int lane = threadIdx.x & 63;
  int row = blockIdx.x * 4 + (threadIdx.x >> 6);  // [0, 16384)
  int b = row >> 12;
  const uint4* ip = (const uint4*)(inp_bf + (size_t)row * F_);
  const float4* vp = (const float4*)(v + b * F_);
  float s = 0.f;
#pragma unroll
  for (int k = 0; k < 2; k++) {
    uint4 x = ip[lane + 64 * k];
    float4 va = vp[(lane + 64 * k) * 2];
    float4 vb = vp[(lane + 64 * k) * 2 + 1];
    s += bflo(x.x) * va.x + bfhi(x.x) * va.y + bflo(x.y) * va.z + bfhi(x.y) * va.w +
         bflo(x.z) * vb.x + bfhi(x.z) * vb.y + bflo(x.w) * vb.z + bfhi(x.w) * vb.w;
  }
  for (int off = 32; off; off >>= 1) s += __shfl_down(s, off);
  if (lane == 0) scores[row] = s + cvec[b];
}

// ---------- K5: softmax over s (per b), in place ----------
__global__ void softmax_kernel(float* __restrict__ sc) {
  __shared__ float red[256];
  int b = blockIdx.x, t = threadIdx.x;
  float* p = sc + b * S_;
  float vals[16];
  float m = -1e30f;
#pragma unroll
  for (int i = 0; i < 16; i++) { vals[i] = p[t + i * 256]; m = fmaxf(m, vals[i]); }
  red[t] = m; __syncthreads();
  for (int o = 128; o; o >>= 1) { if (t < o) red[t] = fmaxf(red[t], red[t + o]); __syncthreads(); }
  m = red[0]; __syncthreads();
  float sum = 0.f;
#pragma unroll
  for (int i = 0; i < 16; i++) { vals[i] = __expf(vals[i] - m); sum += vals[i]; }
  red[t] = sum; __syncthreads();
  for (int o = 128; o; o >>= 1) { if (t < o) red[t] += red[t + o]; __syncthreads(); }
  float inv = 1.f / red[0];
#pragma unroll
  for (int i = 0; i < 16; i++) p[t + i * 256] = vals[i] * inv;
}

// ---------- K6: u[b,f] = sum_s w[b,s] * inp_bf[b,s,f] ----------
__global__ void u_kernel(const unsigned short* __restrict__ inp_bf,
                         const float* __restrict__ w, float* __restrict__ u) {
  int b = blockIdx.z, fc = blockIdx.y, sc = blockIdx.x;  // 32 x 2 x 4
  int t = threadIdx.x;
  int f2 = fc * 512 + t * 2;
  int s0 = sc * 128;
  const float* wp = w + b * S_ + s0;
  const unsigned short* ip = inp_bf + ((size_t)(b * S_ + s0)) * F_ + f2;
  float a0 = 0.f, a1 = 0.f;
  for (int s = 0; s < 128; s++) {
    unsigned int xv = *(const unsigned int*)&ip[(size_t)s * F_];
    float ws = wp[s];
    a0 += ws * bflo(xv);
    a1 += ws * bfhi(xv);
  }
  atomicAdd(&u[b * F_ + f2], a0);
  atomicAdd(&u[b * F_ + f2 + 1], a1);
}

// ---------- K7: ctx[b,a] = u[b,:] . Wv[a,:] + b_v[a] ----------
__global__ void ctx_kernel(const float* __restrict__ u, const float* __restrict__ W,
                           const float* __restrict__ bias, float* __restrict__ ctx) {
  int gw = blockIdx.x * 4 + (threadIdx.x >> 6);
  int lane = threadIdx.x & 63;
  int b = gw >> 9, a = gw & 511;
  const float4* wr = (const float4*)(W + (size_t)(2 * A_ + a) * F_);
  const float4* ur = (const float4*)(u + b * F_);
  float s = 0.f;
#pragma unroll
  for (int k = 0; k < 4; k++) {
    float4 wv = wr[lane + 64 * k], uv = ur[lane + 64 * k];
    s += wv.x * uv.x + wv.y * uv.y + wv.z * uv.z + wv.w * uv.w;
  }
  for (int off = 32; off; off >>= 1) s += __shfl_down(s, off);
  if (lane == 0) ctx[b * A_ + a] = s + bias[2 * A_ + a];
}

// ---------- K8: bf16 GEMM  X[M,1536] = A @ Wslo^T + b, 256x192 tile, 4-phase counted-vmcnt ----------
__global__ __launch_bounds__(512, 2) void gemm_kernel(
    const __hip_bfloat16* __restrict__ Abf,
    const __hip_bfloat16* __restrict__ Wbf,
    const float* __restrict__ bias,
    __hip_bfloat16* __restrict__ X) {
  extern __shared__ unsigned short smem[];
  unsigned short* ldsA = smem;            // 2 bufs x 256x64 = 32768 ushorts
  unsigned short* ldsB = smem + 32768;    // 2 bufs x 192x64 = 24576 ushorts

  int bid = blockIdx.x;
  int swz = (bid & 7) * 64 + (bid >> 3);  // 512 blocks, 8 XCDs, bijective
  int mb = swz >> 3;   // 0..63
  int nb = swz & 7;    // 0..7

  int tid  = threadIdx.x;
  int lane = tid & 63;
  int wv   = tid >> 6;       // 0..7
  int wm   = wv >> 2;        // 0..1  (M half)
  int wn   = wv & 3;         // 0..3  (N quarter: 48 cols)
  int lo   = lane & 15, hi = lane >> 4, sw = lane & 7;

  // swizzled in-row element offsets for the two k-slices (T2: byte ^= (row&7)<<4; row&7==lane&7)
  int bir0 = (((hi * 16)      ^ (sw << 4)) >> 1);
  int bir1 = (((64 + hi * 16) ^ (sw << 4)) >> 1);

  const __hip_bfloat16* Ab = Abf + (size_t)mb * BM * F_;
  const __hip_bfloat16* Bb = Wbf + (size_t)nb * BN * F_;

  // staging: thread t, round q covers row q*64 + (t>>3); source element permuted by the same XOR
  int srow = tid >> 3;                       // 0..63
  int sel  = ((tid & 7) ^ (srow & 7)) * 8;   // element offset within k-slice
  int ldst = wv * 512;                       // wave-uniform LDS base (elements) within a round

  f32x4 acc[8][3];
#pragma unroll
  for (int i = 0; i < 8; i++)
#pragma unroll
    for (int j = 0; j < 3; j++) acc[i][j] = (f32x4){0.f, 0.f, 0.f, 0.f};

  int aBase = (wm * 128 + lo) * 64;  // element base of A reads
  int bBase = (wn * 48 + lo) * 64;   // element base of B reads

#define STAGE(kt_, buf_)                                                                   \
  {                                                                                        \
    int kof_ = (kt_) * BK;                                                                 \
    unsigned short* la_ = ldsA + (buf_) * 16384;                                           \
    unsigned short* lb_ = ldsB + (buf_) * 12288;                                           \
    lds_load16(Ab + (size_t)(srow) * F_ + kof_ + sel,        la_ + 0 * 4096 + ldst);       \
    lds_load16(Ab + (size_t)(64 + srow) * F_ + kof_ + sel,   la_ + 1 * 4096 + ldst);       \
    lds_load16(Ab + (size_t)(128 + srow) * F_ + kof_ + sel,  la_ + 2 * 4096 + ldst);       \
    lds_load16(Ab + (size_t)(192 + srow) * F_ + kof_ + sel,  la_ + 3 * 4096 + ldst);       \
    lds_load16(Bb + (size_t)(srow) * F_ + kof_ + sel,        lb_ + 0 * 4096 + ldst);       \
    lds_load16(Bb + (size_t)(64 + srow) * F_ + kof_ + sel,   lb_ + 1 * 4096 + ldst);       \
    lds_load16(Bb + (size_t)(128 + srow) * F_ + kof_ + sel,  lb_ + 2 * 4096 + ldst);       \
  }

  STAGE(0, 0);

  for (int kt = 0; kt < NT; ++kt) {
    int c = kt & 1;
    __builtin_amdgcn_s_barrier();           // all waves done reading buf 1-c
    if (kt + 1 < NT) {
      STAGE(kt + 1, c ^ 1);                 // 7 loads in flight across compute
      asm volatile("s_waitcnt vmcnt(7)" ::: "memory");   // tile kt's loads landed
    } else {
      asm volatile("s_waitcnt vmcnt(0)" ::: "memory");
    }
    __builtin_amdgcn_s_barrier();           // buf c visible to all waves
    __builtin_amdgcn_sched_barrier(0);

    const unsigned short* la = ldsA + c * 16384;
    const unsigned short* lb = ldsB + c * 12288;

    bf16x8 aq[4][2], b01[2][2], b2[2];

    // ---- phase 0: A quadrant 0 (8 reads) + B cols {0,1} (4 reads); 16 MFMA
#pragma unroll
    for (int i = 0; i < 4; i++) {
      aq[i][0] = *(const bf16x8*)&la[aBase + i * 1024 + bir0];
      aq[i][1] = *(const bf16x8*)&la[aBase + i * 1024 + bir1];
    }
#pragma unroll
    for (int j = 0; j < 2; j++) {
      b01[j][0] = *(const bf16x8*)&lb[bBase + j * 1024 + bir0];
      b01[j][1] = *(const bf16x8*)&lb[bBase + j * 1024 + bir1];
    }
    __builtin_amdgcn_s_setprio(1);
#pragma unroll
    for (int i = 0; i < 4; i++)
#pragma unroll
      for (int j = 0; j < 2; j++) {
        acc[i][j] = __builtin_amdgcn_mfma_f32_16x16x32_bf16(aq[i][0], b01[j][0], acc[i][j], 0, 0, 0);
        acc[i][j] = __builtin_amdgcn_mfma_f32_16x16x32_bf16(aq[i][1], b01[j][1], acc[i][j], 0, 0, 0);
      }
    __builtin_amdgcn_s_setprio(0);
    __builtin_amdgcn_sched_barrier(0);

    // ---- phase 1: B col 2 (2 reads); 8 MFMA
    b2[0] = *(const bf16x8*)&lb[bBase + 2 * 1024 + bir0];
    b2[1] = *(const bf16x8*)&lb[bBase + 2 * 1024 + bir1];
    __builtin_amdgcn_s_setprio(1);
#pragma unroll
    for (int i = 0; i < 4; i++) {
      acc[i][2] = __builtin_amdgcn_mfma_f32_16x16x32_bf16(aq[i][0], b2[0], acc[i][2], 0, 0, 0);
      acc[i][2] = __builtin_amdgcn_mfma_f32_16x16x32_bf16(aq[i][1], b2[1], acc[i][2], 0, 0, 0);
    }
    __builtin_amdgcn_s_setprio(0);
    __builtin_amdgcn_sched_barrier(0);

    // ---- phase 2: A quadrant 1 (8 reads); 8 MFMA
#pragma unroll
    for (int i = 0; i < 4; i++) {
      aq[i][0] = *(const bf16x8*)&la[aBase + 4096 + i * 1024 + bir0];
      aq[i][1] = *(const bf16x8*)&la[aBase + 4096 + i * 1024 + bir1];
    }
    __builtin_amdgcn_s_setprio(1);
#pragma unroll
    for (int i = 0; i < 4; i++) {
      acc[4 + i][2] = __builtin_amdgcn_mfma_f32_16x16x32_bf16(aq[i][0], b2[0], acc[4 + i][2], 0, 0, 0);
      acc[4 + i][2] = __builtin_amdgcn_mfma_f32_16x16x32_bf16(aq[i][1], b2[1], acc[4 + i][2], 0, 0, 0);
    }
    __builtin_amdgcn_s_setprio(0);
    __builtin_amdgcn_sched_barrier(0);

    // ---- phase 3: 16 MFMA (A q1 x B {0,1}, still in regs)
    __builtin_amdgcn_s_setprio(1);
#pragma unroll
    for (int i = 0; i < 4; i++)
#pragma unroll
      for (int j = 0; j < 2; j++) {
        acc[4 + i][j] = __builtin_amdgcn_mfma_f32_16x16x32_bf16(aq[i][0], b01[j][0], acc[4 + i][j], 0, 0, 0);
        acc[4 + i][j] = __builtin_amdgcn_mfma_f32_16x16x32_bf16(aq[i][1], b01[j][1], acc[4 + i][j], 0, 0, 0);
      }
    __builtin_amdgcn_s_setprio(0);
    __builtin_amdgcn_sched_barrier(0);
  }
#undef STAGE

  // epilogue: + bias, f32 -> bf16, store
#pragma unroll
  for (int fm = 0; fm < 8; fm++) {
    int grow = mb * BM + wm * 128 + fm * 16 + hi * 4;
#pragma unroll
    for (int fn = 0; fn < 3; fn++) {
      int gcol = nb * BN + wn * 48 + fn * 16 + lo;
      float bv = bias[gcol];
#pragma unroll
      for (int rg = 0; rg < 4; rg++) {
        X[(size_t)(grow + rg) * N3_ + gcol] = __float2bfloat16(acc[fm][fn][rg] + bv);
      }
    }
  }
}

// ---------- K9: final = (ctx + segmax)*out + local_max ----------
__global__ void final_kernel(const unsigned short* __restrict__ X,
                             const float* __restrict__ ctx,
                             float* __restrict__ out) {
  int b = blockIdx.y, seg = blockIdx.x;  // 4, 64
  int t = threadIdx.x;
  int c0 = t * 2;
  int sbase = seg * 64;

  float m0 = -1e30f, m1 = -1e30f;
  size_t base = ((size_t)b * S_ + sbase) * N3_;
  for (int r = 0; r < 64; r++) {
    unsigned int sv = *(const unsigned int*)&X[base + (size_t)r * N3_ + c0];
    m0 = fmaxf(m0, bflo(sv));
    m1 = fmaxf(m1, bfhi(sv));
  }
  float2 cx = *(const float2*)&ctx[b * A_ + c0];
  float g0 = cx.x + m0, g1 = cx.y + m1;

  auto loadloc = [&](int s) -> unsigned int {
    if ((unsigned)s >= (unsigned)S_) return 0xFF80FF80u;
    return *(const unsigned int*)&X[((size_t)b * S_ + s) * N3_ + A_ + c0];
  };
  unsigned int w0 = loadloc(sbase - 2), w1 = loadloc(sbase - 1);
  unsigned int w2 = loadloc(sbase),     w3 = loadloc(sbase + 1);
  for (int rr = 0; rr < 64; rr++) {
    int s = sbase + rr;
    unsigned int w4 = loadloc(s + 2);
    float lo = fmaxf(fmaxf(fmaxf(bflo(w0), bflo(w1)), fmaxf(bflo(w2), bflo(w3))), bflo(w4));
    float hi = fmaxf(fmaxf(fmaxf(bfhi(w0), bfhi(w1)), fmaxf(bfhi(w2), bfhi(w3))), bfhi(w4));
    unsigned int ov = *(const unsigned int*)&X[((size_t)b * S_ + s) * N3_ + 2 * A_ + c0];
    float2 res;
    res.x = g0 * bflo(ov) + lo;
    res.y = g1 * bfhi(ov) + hi;
    *(float2*)&out[((size_t)b * S_ + s) * A_ + c0] = res;
    w0 = w1; w1 = w2; w2 = w3; w3 = w4;
  }
}

// ---------- launch ----------
extern "C" void kernel_launch(void* const* d_in, const int* in_sizes, int n_in,
                              void* d_out, int out_size, void* d_ws, size_t ws_size,
                              hipStream_t stream) {
  const float* inp  = (const float*)d_in[0];
  const float* W    = (const float*)d_in[1];
  const float* bias = (const float*)d_in[2];
  float* out = (float*)d_out;
  char* ws = (char*)d_ws;

  const size_t X_OFF    = 0;                        // bf16 X: 50,331,648
  const size_t INP_OFF  = 50331648;                 // bf16 inp: 33,554,432
  const size_t W_OFF    = 83886080;                 // bf16 W[1536:3072]: 3,145,728
  const size_t MU_OFF   = 87031808;                 // f32 mu: 16,384
  const size_t U_OFF    = MU_OFF + 16384;           // f32 u: 16,384
  const size_t V_OFF    = U_OFF + 16384;            // f32 v: 16,384
  const size_t CV_OFF   = V_OFF + 16384;            // f32 cvec: 256
  const size_t AGG_OFF  = CV_OFF + 256;             // f32 agg: 8,192
  const size_t CTX_OFF  = AGG_OFF + 8192;           // f32 ctx: 8,192
  const size_t SC_OFF   = CTX_OFF + 8192;           // f32 scores: 65,536

  unsigned short* xbf    = (unsigned short*)(ws + X_OFF);
  unsigned short* inp_bf = (unsigned short*)(ws + INP_OFF);
  unsigned short* w_bf   = (unsigned short*)(ws + W_OFF);
  float* mu     = (float*)(ws + MU_OFF);
  float* u      = (float*)(ws + U_OFF);
  float* v      = (float*)(ws + V_OFF);
  float* cvec   = (float*)(ws + CV_OFF);
  float* agg    = (float*)(ws + AGG_OFF);
  float* ctx    = (float*)(ws + CTX_OFF);
  float* scores = (float*)(ws + SC_OFF);

  static int lds_attr_set = 0;
  (void)lds_attr_set;
  hipFuncSetAttribute(reinterpret_cast<const void*>(gemm_kernel),
                      hipFuncAttributeMaxDynamicSharedMemorySize, 114688);

  hipMemsetAsync(ws + MU_OFF, 0, 3 * 16384 + 256, stream);  // zero mu, u, v, cvec
  convert_mean_kernel<<<512, 256, 0, stream>>>(inp, W, inp_bf, w_bf, mu);
  gemm_kernel<<<512, 512, 114688, stream>>>((const __hip_bfloat16*)inp_bf,
                                            (const __hip_bfloat16*)w_bf,
                                            bias + 3 * A_, (__hip_bfloat16*)xbf);
  agg_kernel<<<512, 256, 0, stream>>>(mu, W, bias, agg);
  v_kernel<<<dim3(4, 8), 256, 0, stream>>>(agg, W, bias, v, cvec);
  scores_kernel<<<4096, 256, 0, stream>>>(inp_bf, v, cvec, scores);
  softmax_kernel<<<4, 256, 0, stream>>>(scores);
  u_kernel<<<dim3(32, 2, 4), 256, 0, stream>>>(inp_bf, scores, u);
  ctx_kernel<<<512, 256, 0, stream>>>(u, W, bias, ctx);
  final_kernel<<<dim3(64, 4), 256, 0, stream>>>(xbf, ctx, out);
}

// Round 5
// 128.062 us; speedup vs baseline: 1.9155x; 1.1813x over previous
//
#include <hip/hip_runtime.h>
#include <hip/hip_bf16.h>
#include <stdint.h>

#define B_    4
#define S_    4096
#define F_    1024
#define A_    512
#define N3_   1536
#define M_    16384

#define BM    256
#define BK    64
#define NT    (F_ / BK)   // 16 K-tiles
#define LDP   266         // Xt col-major stride (elems); 133 words % 32 = 5 -> conflict-free

typedef __attribute__((ext_vector_type(8))) __bf16 bf16x8;
typedef __attribute__((ext_vector_type(4))) float  f32x4;

// ---------- helpers ----------
__device__ __forceinline__ float bflo(unsigned int u) {
  union { unsigned int i; float f; } v; v.i = u << 16; return v.f;
}
__device__ __forceinline__ float bfhi(unsigned int u) {
  union { unsigned int i; float f; } v; v.i = u & 0xffff0000u; return v.f;
}
__device__ __forceinline__ float bf1(unsigned short u) {
  union { unsigned int i; float f; } v; v.i = ((unsigned int)u) << 16; return v.f;
}
__device__ __forceinline__ unsigned short bfc(float f) {
  return __builtin_bit_cast(unsigned short, __float2bfloat16(f));
}

__device__ __forceinline__ ushort4 cvt_bf4(float4 v) {
  ushort4 o;
  o.x = bfc(v.x); o.y = bfc(v.y); o.z = bfc(v.z); o.w = bfc(v.w);
  return o;
}

typedef __attribute__((address_space(3))) unsigned int lds_uint;
typedef const __attribute__((address_space(1))) unsigned int glob_uint;
__device__ __forceinline__ void lds_load16(const void* g, void* l) {
  __builtin_amdgcn_global_load_lds((glob_uint*)g, (lds_uint*)l, 16, 0, 0);
}

// ---------- K1: convert inp -> bf16 (+ column sums for mean), W[1536:3072] -> bf16 ----------
__global__ __launch_bounds__(256) void convert_mean_kernel(
    const float* __restrict__ inp, const float* __restrict__ W,
    unsigned short* __restrict__ inp_bf, unsigned short* __restrict__ w_bf,
    float* __restrict__ mu) {
  int blk = blockIdx.x;   // 512
  int t   = threadIdx.x;  // 256
  int r0  = blk * 32;
  int b   = r0 >> 12;
  float acc0 = 0.f, acc1 = 0.f, acc2 = 0.f, acc3 = 0.f;
  for (int r = 0; r < 32; r++) {
    size_t row = (size_t)(r0 + r);
    float4 v = ((const float4*)(inp + row * F_))[t];
    acc0 += v.x; acc1 += v.y; acc2 += v.z; acc3 += v.w;
    ((ushort4*)(inp_bf + row * F_))[t] = cvt_bf4(v);
  }
  atomicAdd(&mu[b * F_ + t * 4 + 0], acc0);
  atomicAdd(&mu[b * F_ + t * 4 + 1], acc1);
  atomicAdd(&mu[b * F_ + t * 4 + 2], acc2);
  atomicAdd(&mu[b * F_ + t * 4 + 3], acc3);

  const float* Wc = W + (size_t)N3_ * F_;
  const int n4 = (N3_ * F_) / 4;
  for (int i = blk * 256 + t; i < n4; i += 512 * 256) {
    ((ushort4*)w_bf)[i] = cvt_bf4(((const float4*)Wc)[i]);
  }
}

// ---------- K2: agg[b,a] = (mu[b,:]/S) . Wq[a,:] + b_q[a] ----------
__global__ void agg_kernel(const float* __restrict__ mu, const float* __restrict__ W,
                           const float* __restrict__ bias, float* __restrict__ agg) {
  int gw = blockIdx.x * 4 + (threadIdx.x >> 6);
  int lane = threadIdx.x & 63;
  int b = gw >> 9, a = gw & 511;
  const float4* wr = (const float4*)(W + (size_t)a * F_);
  const float4* mr = (const float4*)(mu + b * F_);
  float s = 0.f;
#pragma unroll
  for (int k = 0; k < 4; k++) {
    float4 wv = wr[lane + 64 * k], mv = mr[lane + 64 * k];
    s += wv.x * mv.x + wv.y * mv.y + wv.z * mv.z + wv.w * mv.w;
  }
  for (int off = 32; off; off >>= 1) s += __shfl_down(s, off);
  if (lane == 0) agg[b * A_ + a] = s * (1.f / S_) + bias[a];
}

// ---------- K3: v[b,f] += partial;  cvec[b] = agg[b,:].b_k ----------
__global__ void v_kernel(const float* __restrict__ agg, const float* __restrict__ W,
                         const float* __restrict__ bias, float* __restrict__ v,
                         float* __restrict__ cvec) {
  int fc = blockIdx.x;  // 0..3
  int ac = blockIdx.y;  // 0..7
  int t = threadIdx.x;
  int f = fc * 256 + t;
  const float* Wk = W + (size_t)A_ * F_;
  float s0 = 0.f, s1 = 0.f, s2 = 0.f, s3 = 0.f;
  int a0 = ac * 64;
  for (int a = a0; a < a0 + 64; a++) {
    float wv = Wk[(size_t)a * F_ + f];
    s0 += agg[a] * wv;
    s1 += agg[A_ + a] * wv;
    s2 += agg[2 * A_ + a] * wv;
    s3 += agg[3 * A_ + a] * wv;
  }
  atomicAdd(&v[f], s0);
  atomicAdd(&v[F_ + f], s1);
  atomicAdd(&v[2 * F_ + f], s2);
  atomicAdd(&v[3 * F_ + f], s3);

  if (fc == 0 && ac == 0) {
    int bb = t >> 6, l = t & 63;
    float c = 0.f;
#pragma unroll
    for (int i = 0; i < 8; i++) c += agg[bb * A_ + l + 64 * i] * bias[A_ + l + 64 * i];
    for (int off = 32; off; off >>= 1) c += __shfl_down(c, off);
    if (l == 0) cvec[bb] = c;
  }
}

// ---------- K4: scores[b,s] = v[b,:] . inp_bf[b,s,:] + c[b] ----------
__global__ void scores_kernel(const unsigned short* __restrict__ inp_bf,
                              const float* __restrict__ v,
                              const float* __restrict__ cvec, float* __restrict__ scores) {
  int lane = threadIdx.x & 63;
  int row = blockIdx.x * 4 + (threadIdx.x >> 6);
  int b = row >> 12;
  const uint4* ip = (const uint4*)(inp_bf + (size_t)row * F_);
  const float4* vp = (const float4*)(v + b * F_);
  float s = 0.f;
#pragma unroll
  for (int k = 0; k < 2; k++) {
    uint4 x = ip[lane + 64 * k];
    float4 va = vp[(lane + 64 * k) * 2];
    float4 vb = vp[(lane + 64 * k) * 2 + 1];
    s += bflo(x.x) * va.x + bfhi(x.x) * va.y + bflo(x.y) * va.z + bfhi(x.y) * va.w +
         bflo(x.z) * vb.x + bfhi(x.z) * vb.y + bflo(x.w) * vb.z + bfhi(x.w) * vb.w;
  }
  for (int off = 32; off; off >>= 1) s += __shfl_down(s, off);
  if (lane == 0) scores[row] = s + cvec[b];
}

// ---------- K5: softmax ----------
__global__ void softmax_kernel(float* __restrict__ sc) {
  __shared__ float red[256];
  int b = blockIdx.x, t = threadIdx.x;
  float* p = sc + b * S_;
  float vals[16];
  float m = -1e30f;
#pragma unroll
  for (int i = 0; i < 16; i++) { vals[i] = p[t + i * 256]; m = fmaxf(m, vals[i]); }
  red[t] = m; __syncthreads();
  for (int o = 128; o; o >>= 1) { if (t < o) red[t] = fmaxf(red[t], red[t + o]); __syncthreads(); }
  m = red[0]; __syncthreads();
  float sum = 0.f;
#pragma unroll
  for (int i = 0; i < 16; i++) { vals[i] = __expf(vals[i] - m); sum += vals[i]; }
  red[t] = sum; __syncthreads();
  for (int o = 128; o; o >>= 1) { if (t < o) red[t] += red[t + o]; __syncthreads(); }
  float inv = 1.f / red[0];
#pragma unroll
  for (int i = 0; i < 16; i++) p[t + i * 256] = vals[i] * inv;
}

// ---------- K6: u[b,f] = sum_s w[b,s] * inp_bf[b,s,f] ----------
__global__ void u_kernel(const unsigned short* __restrict__ inp_bf,
                         const float* __restrict__ w, float* __restrict__ u) {
  int b = blockIdx.z, fc = blockIdx.y, sc = blockIdx.x;
  int t = threadIdx.x;
  int f2 = fc * 512 + t * 2;
  int s0 = sc * 128;
  const float* wp = w + b * S_ + s0;
  const unsigned short* ip = inp_bf + ((size_t)(b * S_ + s0)) * F_ + f2;
  float a0 = 0.f, a1 = 0.f;
  for (int s = 0; s < 128; s++) {
    unsigned int xv = *(const unsigned int*)&ip[(size_t)s * F_];
    float ws = wp[s];
    a0 += ws * bflo(xv);
    a1 += ws * bfhi(xv);
  }
  atomicAdd(&u[b * F_ + f2], a0);
  atomicAdd(&u[b * F_ + f2 + 1], a1);
}

// ---------- K7: ctx[b,a] = u[b,:] . Wv[a,:] + b_v[a] ----------
__global__ void ctx_kernel(const float* __restrict__ u, const float* __restrict__ W,
                           const float* __restrict__ bias, float* __restrict__ ctx) {
  int gw = blockIdx.x * 4 + (threadIdx.x >> 6);
  int lane = threadIdx.x & 63;
  int b = gw >> 9, a = gw & 511;
  const float4* wr = (const float4*)(W + (size_t)(2 * A_ + a) * F_);
  const float4* ur = (const float4*)(u + b * F_);
  float s = 0.f;
#pragma unroll
  for (int k = 0; k < 4; k++) {
    float4 wv = wr[lane + 64 * k], uv = ur[lane + 64 * k];
    s += wv.x * uv.x + wv.y * uv.y + wv.z * uv.z + wv.w * uv.w;
  }
  for (int off = 32; off; off >>= 1) s += __shfl_down(s, off);
  if (lane == 0) ctx[b * A_ + a] = s + bias[2 * A_ + a];
}

// ---------- K8: fused GEMM + final  ----------
// Tile 256 rows x 192 cols, where cols = 64-col strip nb from each of {seg, loc, out}.
// K-loop: 3 phases/K-tile (m201 skeleton), counted vmcnt. Epilogue: acc -> LDS Xt
// (col-major, stride 266), segmax + rolling loc window + (ctx+segmax)*out -> d_out.
__global__ __launch_bounds__(512, 2) void gemm_fused(
    const __hip_bfloat16* __restrict__ Abf,
    const __hip_bfloat16* __restrict__ Wbf,
    const float* __restrict__ biasP,   // bias + 1536
    const float* __restrict__ ctx,
    float* __restrict__ out,
    unsigned short* __restrict__ sideLoc,
    float* __restrict__ sideGO) {
  extern __shared__ unsigned short smem[];
  unsigned short* ldsA = smem;            // 2 x 16384 elems (2 x 32 KB)
  unsigned short* ldsB = smem + 32768;    // 2 x 12288 elems (2 x 24 KB)
  unsigned short* Xt   = smem;            // epilogue alias: [192 cols][266 rows]
  float* segred = (float*)((char*)smem + 192 * LDP * 2);  // 4 x 64 f32

  int bid = blockIdx.x;
  int swz = (bid & 7) * 64 + (bid >> 3);  // 512 blocks, 8 XCDs, bijective
  int mb = swz >> 3;   // 0..63
  int nb = swz & 7;    // 0..7

  int tid  = threadIdx.x;
  int lane = tid & 63;
  int wv   = tid >> 6;       // 0..7
  int wm   = wv >> 1;        // 0..3 : 64-row slice (one full segment)
  int wn   = wv & 1;         // 0..1 : 96-col slice
  int lo   = lane & 15, hi = lane >> 4, sw = lane & 7;

  int bir0 = (((hi * 16)      ^ (sw << 4)) >> 1);
  int bir1 = (((64 + hi * 16) ^ (sw << 4)) >> 1);

  const __hip_bfloat16* Ab = Abf + (size_t)mb * BM * F_;

  int srow = tid >> 3;                       // 0..63
  int sel  = ((tid & 7) ^ (srow & 7)) * 8;
  int ldst = wv * 512;

  f32x4 acc[4][6];
#pragma unroll
  for (int i = 0; i < 4; i++)
#pragma unroll
    for (int j = 0; j < 6; j++) acc[i][j] = (f32x4){0.f, 0.f, 0.f, 0.f};

  int aBase = (wm * 64 + lo) * 64;
  int bBase = (wn * 96 + lo) * 64;

#define STG_A(kt_, buf_, r_)                                                              \
  lds_load16(Ab + (size_t)((r_) * 64 + srow) * F_ + (kt_) * BK + sel,                     \
             ldsA + (buf_) * 16384 + (r_) * 4096 + ldst)
#define STG_B(kt_, buf_, q_)                                                              \
  lds_load16(Wbf + (size_t)((q_) * 512 + nb * 64 + srow) * F_ + (kt_) * BK + sel,         \
             ldsB + (buf_) * 12288 + (q_) * 4096 + ldst)

  // prologue: full stage of tile 0
  STG_A(0, 0, 0); STG_A(0, 0, 1); STG_A(0, 0, 2); STG_A(0, 0, 3);
  STG_B(0, 0, 0); STG_B(0, 0, 1); STG_B(0, 0, 2);

  for (int kt = 0; kt < NT; ++kt) {
    int c = kt & 1, nx = c ^ 1;
    bool pf = (kt + 1 < NT);
    const unsigned short* la = ldsA + c * 16384;
    const unsigned short* lb = ldsB + c * 12288;
    bf16x8 af[4][2], bfr[2][2];

    // ---- phase 0: stage chunk0 + counted wait; read A(8) + B cols 0,1 (4); 16 MFMA
    if (pf) {
      STG_A(kt + 1, nx, 0); STG_A(kt + 1, nx, 1); STG_A(kt + 1, nx, 2);
      asm volatile("s_waitcnt vmcnt(3)" ::: "memory");
    } else {
      asm volatile("s_waitcnt vmcnt(0)" ::: "memory");
    }
    __builtin_amdgcn_s_barrier();
#pragma unroll
    for (int i = 0; i < 4; i++) {
      af[i][0] = *(const bf16x8*)&la[aBase + i * 1024 + bir0];
      af[i][1] = *(const bf16x8*)&la[aBase + i * 1024 + bir1];
    }
#pragma unroll
    for (int j = 0; j < 2; j++) {
      bfr[j][0] = *(const bf16x8*)&lb[bBase + j * 1024 + bir0];
      bfr[j][1] = *(const bf16x8*)&lb[bBase + j * 1024 + bir1];
    }
    asm volatile("s_waitcnt lgkmcnt(0)" ::: "memory");
    __builtin_amdgcn_sched_barrier(0);
    __builtin_amdgcn_s_setprio(1);
#pragma unroll
    for (int i = 0; i < 4; i++)
#pragma unroll
      for (int j = 0; j < 2; j++) {
        acc[i][j] = __builtin_amdgcn_mfma_f32_16x16x32_bf16(af[i][0], bfr[j][0], acc[i][j], 0, 0, 0);
        acc[i][j] = __builtin_amdgcn_mfma_f32_16x16x32_bf16(af[i][1], bfr[j][1], acc[i][j], 0, 0, 0);
      }
    __builtin_amdgcn_s_setprio(0);
    __builtin_amdgcn_s_barrier();

    // ---- phase 1: read B cols 2,3; stage chunk1; 16 MFMA
#pragma unroll
    for (int j = 0; j < 2; j++) {
      bfr[j][0] = *(const bf16x8*)&lb[bBase + (2 + j) * 1024 + bir0];
      bfr[j][1] = *(const bf16x8*)&lb[bBase + (2 + j) * 1024 + bir1];
    }
    if (pf) { STG_A(kt + 1, nx, 3); STG_B(kt + 1, nx, 0); }
    __builtin_amdgcn_s_barrier();
    asm volatile("s_waitcnt lgkmcnt(0)" ::: "memory");
    __builtin_amdgcn_sched_barrier(0);
    __builtin_amdgcn_s_setprio(1);
#pragma unroll
    for (int i = 0; i < 4; i++)
#pragma unroll
      for (int j = 0; j < 2; j++) {
        acc[i][2 + j] = __builtin_amdgcn_mfma_f32_16x16x32_bf16(af[i][0], bfr[j][0], acc[i][2 + j], 0, 0, 0);
        acc[i][2 + j] = __builtin_amdgcn_mfma_f32_16x16x32_bf16(af[i][1], bfr[j][1], acc[i][2 + j], 0, 0, 0);
      }
    __builtin_amdgcn_s_setprio(0);
    __builtin_amdgcn_s_barrier();

    // ---- phase 2: read B cols 4,5; stage chunk2; 16 MFMA
#pragma unroll
    for (int j = 0; j < 2; j++) {
      bfr[j][0] = *(const bf16x8*)&lb[bBase + (4 + j) * 1024 + bir0];
      bfr[j][1] = *(const bf16x8*)&lb[bBase + (4 + j) * 1024 + bir1];
    }
    if (pf) { STG_B(kt + 1, nx, 1); STG_B(kt + 1, nx, 2); }
    __builtin_amdgcn_s_barrier();
    asm volatile("s_waitcnt lgkmcnt(0)" ::: "memory");
    __builtin_amdgcn_sched_barrier(0);
    __builtin_amdgcn_s_setprio(1);
#pragma unroll
    for (int i = 0; i < 4; i++)
#pragma unroll
      for (int j = 0; j < 2; j++) {
        acc[i][4 + j] = __builtin_amdgcn_mfma_f32_16x16x32_bf16(af[i][0], bfr[j][0], acc[i][4 + j], 0, 0, 0);
        acc[i][4 + j] = __builtin_amdgcn_mfma_f32_16x16x32_bf16(af[i][1], bfr[j][1], acc[i][4 + j], 0, 0, 0);
      }
    __builtin_amdgcn_s_setprio(0);
    __builtin_amdgcn_s_barrier();
  }
#undef STG_A
#undef STG_B

  // ---------------- epilogue ----------------
  // 1) acc (+bias) -> Xt col-major bf16. (All LDS reads of staging done: lgkm0 + barrier.)
  float bias_r[6];
#pragma unroll
  for (int fj = 0; fj < 6; fj++) {
    int cl = wn * 96 + fj * 16 + lo;
    bias_r[fj] = biasP[(cl >> 6) * 512 + nb * 64 + (cl & 63)];
  }
#pragma unroll
  for (int fi = 0; fi < 4; fi++) {
#pragma unroll
    for (int fj = 0; fj < 6; fj++) {
      int cl = wn * 96 + fj * 16 + lo;
      int r  = wm * 64 + fi * 16 + hi * 4;
      float v0 = acc[fi][fj][0] + bias_r[fj];
      float v1 = acc[fi][fj][1] + bias_r[fj];
      float v2 = acc[fi][fj][2] + bias_r[fj];
      float v3 = acc[fi][fj][3] + bias_r[fj];
      unsigned int u01 = (unsigned int)bfc(v0) | ((unsigned int)bfc(v1) << 16);
      unsigned int u23 = (unsigned int)bfc(v2) | ((unsigned int)bfc(v3) << 16);
      *(unsigned int*)&Xt[cl * LDP + r]     = u01;
      *(unsigned int*)&Xt[cl * LDP + r + 2] = u23;
    }
  }
  __syncthreads();

  // 2) segment maxes: seg chunk = Xt cols 0..63
  if (tid < 256) {
    int seg = tid >> 6, c = tid & 63;
    int base = c * LDP + seg * 64;
    float m = -1e30f;
#pragma unroll
    for (int k = 0; k < 32; k++) {
      unsigned int u = *(const unsigned int*)&Xt[base + 2 * k];
      m = fmaxf(m, fmaxf(bflo(u), bfhi(u)));
    }
    segred[seg * 64 + c] = m;
  }
  __syncthreads();

  // 3) final combine: wave wv owns rows wv*32..+31, lane = col c (0..63)
  {
    int c  = lane;
    int r0 = wv * 32;
    int b  = mb >> 4;
    int gcol = nb * 64 + c;
    float g = ctx[b * 512 + gcol] + segred[(r0 >> 6) * 64 + c];
    int lbase = (64 + c) * LDP;
    int obase = (128 + c) * LDP;
    float lw0 = bf1(Xt[lbase + max(r0 - 2, 0)]);
    float lw1 = bf1(Xt[lbase + max(r0 - 1, 0)]);
    float lw2 = bf1(Xt[lbase + r0]);
    float lw3 = bf1(Xt[lbase + r0 + 1]);
    size_t obase_g = ((size_t)(mb * 256 + r0)) * 512 + gcol;
#pragma unroll
    for (int j = 0; j < 32; j++) {
      int rn = min(r0 + j + 2, 255);
      float lw4 = bf1(Xt[lbase + rn]);
      float lm = fmaxf(fmaxf(fmaxf(lw0, lw1), fmaxf(lw2, lw3)), lw4);
      float o = bf1(Xt[obase + r0 + j]);
      out[obase_g + (size_t)j * 512] = g * o + lm;
      lw0 = lw1; lw1 = lw2; lw2 = lw3; lw3 = lw4;
    }
  }

  // 4) side buffers for tile-boundary loc-window fixup (rows 0,1,254,255)
  if (tid < 256) {
    int rsel = tid >> 6, c = tid & 63;
    int r = (rsel < 2) ? rsel : (252 + rsel);   // 0,1,254,255
    int b = mb >> 4;
    float g = ctx[b * 512 + nb * 64 + c] + segred[(r >> 6) * 64 + c];
    float o = bf1(Xt[(128 + c) * LDP + r]);
    int gr = mb * 4 + rsel;
    sideLoc[gr * 512 + nb * 64 + c] = Xt[(64 + c) * LDP + r];
    sideGO[gr * 512 + nb * 64 + c]  = g * o;
  }
}

// ---------- K9: fixup for loc windows crossing 256-row tile boundaries ----------
__global__ void fixup_kernel(const unsigned short* __restrict__ sideLoc,
                             const float* __restrict__ sideGO,
                             float* __restrict__ out) {
  int rb = blockIdx.x;      // 0..63
  int tb = rb & 15;         // tile index within b
  int t = threadIdx.x;      // 256
  int rsel = t >> 6, cq = t & 63;
#pragma unroll
  for (int k = 0; k < 8; k++) {
    int c = cq * 8 + k;
    float miss;
    int rl;
    if (rsel == 0) {
      if (tb == 0) continue;
      miss = fmaxf(bf1(sideLoc[((rb - 1) * 4 + 2) * 512 + c]),
                   bf1(sideLoc[((rb - 1) * 4 + 3) * 512 + c]));
      rl = 0;
    } else if (rsel == 1) {
      if (tb == 0) continue;
      miss = bf1(sideLoc[((rb - 1) * 4 + 3) * 512 + c]);
      rl = 1;
    } else if (rsel == 2) {
      if (tb == 15) continue;
      miss = bf1(sideLoc[((rb + 1) * 4 + 0) * 512 + c]);
      rl = 254;
    } else {
      if (tb == 15) continue;
      miss = fmaxf(bf1(sideLoc[((rb + 1) * 4 + 0) * 512 + c]),
                   bf1(sideLoc[((rb + 1) * 4 + 1) * 512 + c]));
      rl = 255;
    }
    size_t oi = ((size_t)rb * 256 + rl) * 512 + c;
    float cand = sideGO[(rb * 4 + rsel) * 512 + c] + miss;
    out[oi] = fmaxf(out[oi], cand);
  }
}

// ---------- launch ----------
extern "C" void kernel_launch(void* const* d_in, const int* in_sizes, int n_in,
                              void* d_out, int out_size, void* d_ws, size_t ws_size,
                              hipStream_t stream) {
  const float* inp  = (const float*)d_in[0];
  const float* W    = (const float*)d_in[1];
  const float* bias = (const float*)d_in[2];
  float* out = (float*)d_out;
  char* ws = (char*)d_ws;

  const size_t INP_OFF  = 0;                   // bf16 inp: 33,554,432
  const size_t W_OFF    = 33554432;            // bf16 W[1536:3072]: 3,145,728
  const size_t MU_OFF   = 36700160;            // f32 mu: 16,384
  const size_t U_OFF    = MU_OFF + 16384;
  const size_t V_OFF    = U_OFF + 16384;
  const size_t CV_OFF   = V_OFF + 16384;       // 256
  const size_t AGG_OFF  = CV_OFF + 256;        // 8,192
  const size_t CTX_OFF  = AGG_OFF + 8192;      // 8,192
  const size_t SC_OFF   = CTX_OFF + 8192;      // 65,536
  const size_t SL_OFF   = SC_OFF + 65536;      // sideLoc bf16: 64*4*512*2 = 262,144
  const size_t SG_OFF   = SL_OFF + 262144;     // sideGO f32: 524,288

  unsigned short* inp_bf = (unsigned short*)(ws + INP_OFF);
  unsigned short* w_bf   = (unsigned short*)(ws + W_OFF);
  float* mu     = (float*)(ws + MU_OFF);
  float* u      = (float*)(ws + U_OFF);
  float* v      = (float*)(ws + V_OFF);
  float* cvec   = (float*)(ws + CV_OFF);
  float* agg    = (float*)(ws + AGG_OFF);
  float* ctx    = (float*)(ws + CTX_OFF);
  float* scores = (float*)(ws + SC_OFF);
  unsigned short* sideLoc = (unsigned short*)(ws + SL_OFF);
  float* sideGO = (float*)(ws + SG_OFF);

  hipFuncSetAttribute(reinterpret_cast<const void*>(gemm_fused),
                      hipFuncAttributeMaxDynamicSharedMemorySize, 114688);

  hipMemsetAsync(ws + MU_OFF, 0, 3 * 16384 + 256, stream);  // zero mu, u, v, cvec
  convert_mean_kernel<<<512, 256, 0, stream>>>(inp, W, inp_bf, w_bf, mu);
  agg_kernel<<<512, 256, 0, stream>>>(mu, W, bias, agg);
  v_kernel<<<dim3(4, 8), 256, 0, stream>>>(agg, W, bias, v, cvec);
  scores_kernel<<<4096, 256, 0, stream>>>(inp_bf, v, cvec, scores);
  softmax_kernel<<<4, 256, 0, stream>>>(scores);
  u_kernel<<<dim3(32, 2, 4), 256, 0, stream>>>(inp_bf, scores, u);
  ctx_kernel<<<512, 256, 0, stream>>>(u, W, bias, ctx);
  gemm_fused<<<512, 512, 114688, stream>>>((const __hip_bfloat16*)inp_bf,
                                           (const __hip_bfloat16*)w_bf,
                                           bias + 3 * A_, ctx, out, sideLoc, sideGO);
  fixup_kernel<<<64, 256, 0, stream>>>(sideLoc, sideGO, out);
}

// Round 6
// 126.764 us; speedup vs baseline: 1.9352x; 1.0102x over previous
//
#include <hip/hip_runtime.h>
#include <hip/hip_bf16.h>
#include <stdint.h>

#define B_    4
#define S_    4096
#define F_    1024
#define A_    512
#define N3_   1536
#define M_    16384

#define BM    256
#define BK    64
#define NT    (F_ / BK)   // 16 K-tiles
#define LDP   266         // Xt col-major stride (elems)

typedef __attribute__((ext_vector_type(8))) __bf16 bf16x8;
typedef __attribute__((ext_vector_type(4))) float  f32x4;

#define MFMA(a, b, c) __builtin_amdgcn_mfma_f32_16x16x32_bf16((a), (b), (c), 0, 0, 0)

// ---------- helpers ----------
__device__ __forceinline__ float bflo(unsigned int u) {
  union { unsigned int i; float f; } v; v.i = u << 16; return v.f;
}
__device__ __forceinline__ float bfhi(unsigned int u) {
  union { unsigned int i; float f; } v; v.i = u & 0xffff0000u; return v.f;
}
__device__ __forceinline__ float bf1(unsigned short u) {
  union { unsigned int i; float f; } v; v.i = ((unsigned int)u) << 16; return v.f;
}
__device__ __forceinline__ unsigned short bfc(float f) {
  return __builtin_bit_cast(unsigned short, __float2bfloat16(f));
}

__device__ __forceinline__ ushort4 cvt_bf4(float4 v) {
  ushort4 o;
  o.x = bfc(v.x); o.y = bfc(v.y); o.z = bfc(v.z); o.w = bfc(v.w);
  return o;
}

typedef __attribute__((address_space(3))) unsigned int lds_uint;
typedef const __attribute__((address_space(1))) unsigned int glob_uint;
__device__ __forceinline__ void lds_load16(const void* g, void* l) {
  __builtin_amdgcn_global_load_lds((glob_uint*)g, (lds_uint*)l, 16, 0, 0);
}

// ---------- K1: convert inp -> bf16 (+ column sums for mean), W[1536:3072] -> bf16 ----------
__global__ __launch_bounds__(256) void convert_mean_kernel(
    const float* __restrict__ inp, const float* __restrict__ W,
    unsigned short* __restrict__ inp_bf, unsigned short* __restrict__ w_bf,
    float* __restrict__ mu) {
  int blk = blockIdx.x;   // 512
  int t   = threadIdx.x;  // 256
  int r0  = blk * 32;
  int b   = r0 >> 12;
  float acc0 = 0.f, acc1 = 0.f, acc2 = 0.f, acc3 = 0.f;
  for (int r = 0; r < 32; r++) {
    size_t row = (size_t)(r0 + r);
    float4 v = ((const float4*)(inp + row * F_))[t];
    acc0 += v.x; acc1 += v.y; acc2 += v.z; acc3 += v.w;
    ((ushort4*)(inp_bf + row * F_))[t] = cvt_bf4(v);
  }
  atomicAdd(&mu[b * F_ + t * 4 + 0], acc0);
  atomicAdd(&mu[b * F_ + t * 4 + 1], acc1);
  atomicAdd(&mu[b * F_ + t * 4 + 2], acc2);
  atomicAdd(&mu[b * F_ + t * 4 + 3], acc3);

  const float* Wc = W + (size_t)N3_ * F_;
  const int n4 = (N3_ * F_) / 4;
  for (int i = blk * 256 + t; i < n4; i += 512 * 256) {
    ((ushort4*)w_bf)[i] = cvt_bf4(((const float4*)Wc)[i]);
  }
}

// ---------- K2: agg[b,a] = (mu[b,:]/S) . Wq[a,:] + b_q[a] ----------
__global__ void agg_kernel(const float* __restrict__ mu, const float* __restrict__ W,
                           const float* __restrict__ bias, float* __restrict__ agg) {
  int gw = blockIdx.x * 4 + (threadIdx.x >> 6);
  int lane = threadIdx.x & 63;
  int b = gw >> 9, a = gw & 511;
  const float4* wr = (const float4*)(W + (size_t)a * F_);
  const float4* mr = (const float4*)(mu + b * F_);
  float s = 0.f;
#pragma unroll
  for (int k = 0; k < 4; k++) {
    float4 wv = wr[lane + 64 * k], mv = mr[lane + 64 * k];
    s += wv.x * mv.x + wv.y * mv.y + wv.z * mv.z + wv.w * mv.w;
  }
  for (int off = 32; off; off >>= 1) s += __shfl_down(s, off);
  if (lane == 0) agg[b * A_ + a] = s * (1.f / S_) + bias[a];
}

// ---------- K3: v[b,f] += partial;  cvec[b] = agg[b,:].b_k ----------
__global__ void v_kernel(const float* __restrict__ agg, const float* __restrict__ W,
                         const float* __restrict__ bias, float* __restrict__ v,
                         float* __restrict__ cvec) {
  int fc = blockIdx.x;  // 0..3
  int ac = blockIdx.y;  // 0..7
  int t = threadIdx.x;
  int f = fc * 256 + t;
  const float* Wk = W + (size_t)A_ * F_;
  float s0 = 0.f, s1 = 0.f, s2 = 0.f, s3 = 0.f;
  int a0 = ac * 64;
  for (int a = a0; a < a0 + 64; a++) {
    float wv = Wk[(size_t)a * F_ + f];
    s0 += agg[a] * wv;
    s1 += agg[A_ + a] * wv;
    s2 += agg[2 * A_ + a] * wv;
    s3 += agg[3 * A_ + a] * wv;
  }
  atomicAdd(&v[f], s0);
  atomicAdd(&v[F_ + f], s1);
  atomicAdd(&v[2 * F_ + f], s2);
  atomicAdd(&v[3 * F_ + f], s3);

  if (fc == 0 && ac == 0) {
    int bb = t >> 6, l = t & 63;
    float c = 0.f;
#pragma unroll
    for (int i = 0; i < 8; i++) c += agg[bb * A_ + l + 64 * i] * bias[A_ + l + 64 * i];
    for (int off = 32; off; off >>= 1) c += __shfl_down(c, off);
    if (l == 0) cvec[bb] = c;
  }
}

// ---------- K4: scores[b,s] = v[b,:] . inp_bf[b,s,:] + c[b] ----------
__global__ void scores_kernel(const unsigned short* __restrict__ inp_bf,
                              const float* __restrict__ v,
                              const float* __restrict__ cvec, float* __restrict__ scores) {
  int lane = threadIdx.x & 63;
  int row = blockIdx.x * 4 + (threadIdx.x >> 6);
  int b = row >> 12;
  const uint4* ip = (const uint4*)(inp_bf + (size_t)row * F_);
  const float4* vp = (const float4*)(v + b * F_);
  float s = 0.f;
#pragma unroll
  for (int k = 0; k < 2; k++) {
    uint4 x = ip[lane + 64 * k];
    float4 va = vp[(lane + 64 * k) * 2];
    float4 vb = vp[(lane + 64 * k) * 2 + 1];
    s += bflo(x.x) * va.x + bfhi(x.x) * va.y + bflo(x.y) * va.z + bfhi(x.y) * va.w +
         bflo(x.z) * vb.x + bfhi(x.z) * vb.y + bflo(x.w) * vb.z + bfhi(x.w) * vb.w;
  }
  for (int off = 32; off; off >>= 1) s += __shfl_down(s, off);
  if (lane == 0) scores[row] = s + cvec[b];
}

// ---------- K5: softmax ----------
__global__ void softmax_kernel(float* __restrict__ sc) {
  __shared__ float red[256];
  int b = blockIdx.x, t = threadIdx.x;
  float* p = sc + b * S_;
  float vals[16];
  float m = -1e30f;
#pragma unroll
  for (int i = 0; i < 16; i++) { vals[i] = p[t + i * 256]; m = fmaxf(m, vals[i]); }
  red[t] = m; __syncthreads();
  for (int o = 128; o; o >>= 1) { if (t < o) red[t] = fmaxf(red[t], red[t + o]); __syncthreads(); }
  m = red[0]; __syncthreads();
  float sum = 0.f;
#pragma unroll
  for (int i = 0; i < 16; i++) { vals[i] = __expf(vals[i] - m); sum += vals[i]; }
  red[t] = sum; __syncthreads();
  for (int o = 128; o; o >>= 1) { if (t < o) red[t] += red[t + o]; __syncthreads(); }
  float inv = 1.f / red[0];
#pragma unroll
  for (int i = 0; i < 16; i++) p[t + i * 256] = vals[i] * inv;
}

// ---------- K6: u[b,f] = sum_s w[b,s] * inp_bf[b,s,f] ----------
__global__ void u_kernel(const unsigned short* __restrict__ inp_bf,
                         const float* __restrict__ w, float* __restrict__ u) {
  int b = blockIdx.z, fc = blockIdx.y, sc = blockIdx.x;
  int t = threadIdx.x;
  int f2 = fc * 512 + t * 2;
  int s0 = sc * 128;
  const float* wp = w + b * S_ + s0;
  const unsigned short* ip = inp_bf + ((size_t)(b * S_ + s0)) * F_ + f2;
  float a0 = 0.f, a1 = 0.f;
  for (int s = 0; s < 128; s++) {
    unsigned int xv = *(const unsigned int*)&ip[(size_t)s * F_];
    float ws = wp[s];
    a0 += ws * bflo(xv);
    a1 += ws * bfhi(xv);
  }
  atomicAdd(&u[b * F_ + f2], a0);
  atomicAdd(&u[b * F_ + f2 + 1], a1);
}

// ---------- K7: ctx[b,a] = u[b,:] . Wv[a,:] + b_v[a] ----------
__global__ void ctx_kernel(const float* __restrict__ u, const float* __restrict__ W,
                           const float* __restrict__ bias, float* __restrict__ ctx) {
  int gw = blockIdx.x * 4 + (threadIdx.x >> 6);
  int lane = threadIdx.x & 63;
  int b = gw >> 9, a = gw & 511;
  const float4* wr = (const float4*)(W + (size_t)(2 * A_ + a) * F_);
  const float4* ur = (const float4*)(u + b * F_);
  float s = 0.f;
#pragma unroll
  for (int k = 0; k < 4; k++) {
    float4 wv = wr[lane + 64 * k], uv = ur[lane + 64 * k];
    s += wv.x * uv.x + wv.y * uv.y + wv.z * uv.z + wv.w * uv.w;
  }
  for (int off = 32; off; off >>= 1) s += __shfl_down(s, off);
  if (lane == 0) ctx[b * A_ + a] = s + bias[2 * A_ + a];
}

// ---------- K8: fused GEMM + final, pipelined 3-phase (reads issued under prior MFMA) ----------
__global__ __launch_bounds__(512, 2) void gemm_fused(
    const __hip_bfloat16* __restrict__ Abf,
    const __hip_bfloat16* __restrict__ Wbf,
    const float* __restrict__ biasP,   // bias + 1536
    const float* __restrict__ ctx,
    float* __restrict__ out,
    unsigned short* __restrict__ sideLoc,
    float* __restrict__ sideGO) {
  extern __shared__ unsigned short smem[];
  unsigned short* ldsA = smem;            // 2 x 16384 elems
  unsigned short* ldsB = smem + 32768;    // 2 x 12288 elems
  unsigned short* Xt   = smem;            // epilogue alias: [192 cols][266 rows]
  float* segred = (float*)((char*)smem + 192 * LDP * 2);  // 4 x 64 f32

  int bid = blockIdx.x;
  int swz = (bid & 7) * 64 + (bid >> 3);  // 512 blocks, 8 XCDs, bijective
  int mb = swz >> 3;   // 0..63
  int nb = swz & 7;    // 0..7

  int tid  = threadIdx.x;
  int lane = tid & 63;
  int wv   = tid >> 6;       // 0..7
  int wm   = wv >> 1;        // 0..3 : 64-row slice
  int wn   = wv & 1;         // 0..1 : 96-col slice
  int lo   = lane & 15, hi = lane >> 4, sw = lane & 7;

  int bir0 = (((hi * 16)      ^ (sw << 4)) >> 1);
  int bir1 = (((64 + hi * 16) ^ (sw << 4)) >> 1);

  const __hip_bfloat16* Ab = Abf + (size_t)mb * BM * F_;

  int srow = tid >> 3;                       // 0..63
  int sel  = ((tid & 7) ^ (srow & 7)) * 8;
  int ldst = wv * 512;

  f32x4 acc[4][6];
#pragma unroll
  for (int i = 0; i < 4; i++)
#pragma unroll
    for (int j = 0; j < 6; j++) acc[i][j] = (f32x4){0.f, 0.f, 0.f, 0.f};

  int aBase = (wm * 64 + lo) * 64;
  int bBase = (wn * 96 + lo) * 64;

#define STG_A(kt_, buf_, r_)                                                              \
  lds_load16(Ab + (size_t)((r_) * 64 + srow) * F_ + (kt_) * BK + sel,                     \
             ldsA + (buf_) * 16384 + (r_) * 4096 + ldst)
#define STG_B(kt_, buf_, q_)                                                              \
  lds_load16(Wbf + (size_t)((q_) * 512 + nb * 64 + srow) * F_ + (kt_) * BK + sel,         \
             ldsB + (buf_) * 12288 + (q_) * 4096 + ldst)

  bf16x8 af[4][2], b01[2][2], b23[2][2], b45[2][2];

  // prologue: stage tile 0, wait, read A + B01 of tile 0
  STG_A(0, 0, 0); STG_A(0, 0, 1); STG_A(0, 0, 2); STG_A(0, 0, 3);
  STG_B(0, 0, 0); STG_B(0, 0, 1); STG_B(0, 0, 2);
  asm volatile("s_waitcnt vmcnt(0)" ::: "memory");
  __builtin_amdgcn_s_barrier();
#pragma unroll
  for (int i = 0; i < 4; i++) {
    af[i][0] = *(const bf16x8*)&ldsA[aBase + i * 1024 + bir0];
    af[i][1] = *(const bf16x8*)&ldsA[aBase + i * 1024 + bir1];
  }
#pragma unroll
  for (int j = 0; j < 2; j++) {
    b01[j][0] = *(const bf16x8*)&ldsB[bBase + j * 1024 + bir0];
    b01[j][1] = *(const bf16x8*)&ldsB[bBase + j * 1024 + bir1];
  }

  for (int kt = 0; kt < NT; ++kt) {
    int c = kt & 1, nx = c ^ 1;
    bool pf = (kt + 1 < NT);
    const unsigned short* lb  = ldsB + c * 12288;
    const unsigned short* lan = ldsA + nx * 16384;
    const unsigned short* lbn = ldsB + nx * 12288;

    // ---- phase 0: stage next A; MFMA A x B01; issue B23 reads; barrier
    if (pf) { STG_A(kt + 1, nx, 0); STG_A(kt + 1, nx, 1); STG_A(kt + 1, nx, 2); STG_A(kt + 1, nx, 3); }
    asm volatile("s_waitcnt lgkmcnt(0)" ::: "memory");
    __builtin_amdgcn_sched_barrier(0);
    __builtin_amdgcn_s_setprio(1);
#pragma unroll
    for (int i = 0; i < 4; i++)
#pragma unroll
      for (int j = 0; j < 2; j++) {
        acc[i][j] = MFMA(af[i][0], b01[j][0], acc[i][j]);
        acc[i][j] = MFMA(af[i][1], b01[j][1], acc[i][j]);
      }
    __builtin_amdgcn_s_setprio(0);
#pragma unroll
    for (int j = 0; j < 2; j++) {
      b23[j][0] = *(const bf16x8*)&lb[bBase + (2 + j) * 1024 + bir0];
      b23[j][1] = *(const bf16x8*)&lb[bBase + (2 + j) * 1024 + bir1];
    }
    __builtin_amdgcn_s_barrier();

    // ---- phase 1: stage next B; MFMA A x B23; issue B45 reads; barrier
    if (pf) { STG_B(kt + 1, nx, 0); STG_B(kt + 1, nx, 1); STG_B(kt + 1, nx, 2); }
    asm volatile("s_waitcnt lgkmcnt(0)" ::: "memory");
    __builtin_amdgcn_sched_barrier(0);
    __builtin_amdgcn_s_setprio(1);
#pragma unroll
    for (int i = 0; i < 4; i++)
#pragma unroll
      for (int j = 0; j < 2; j++) {
        acc[i][2 + j] = MFMA(af[i][0], b23[j][0], acc[i][2 + j]);
        acc[i][2 + j] = MFMA(af[i][1], b23[j][1], acc[i][2 + j]);
      }
    __builtin_amdgcn_s_setprio(0);
#pragma unroll
    for (int j = 0; j < 2; j++) {
      b45[j][0] = *(const bf16x8*)&lb[bBase + (4 + j) * 1024 + bir0];
      b45[j][1] = *(const bf16x8*)&lb[bBase + (4 + j) * 1024 + bir1];
    }
    __builtin_amdgcn_s_barrier();

    // ---- phase 2: MFMA A x B45; vmcnt; barrier; read next tile's A + B01
    asm volatile("s_waitcnt lgkmcnt(0)" ::: "memory");
    __builtin_amdgcn_sched_barrier(0);
    __builtin_amdgcn_s_setprio(1);
#pragma unroll
    for (int i = 0; i < 4; i++)
#pragma unroll
      for (int j = 0; j < 2; j++) {
        acc[i][4 + j] = MFMA(af[i][0], b45[j][0], acc[i][4 + j]);
        acc[i][4 + j] = MFMA(af[i][1], b45[j][1], acc[i][4 + j]);
      }
    __builtin_amdgcn_s_setprio(0);
    if (pf) asm volatile("s_waitcnt vmcnt(0)" ::: "memory");
    __builtin_amdgcn_s_barrier();
    if (pf) {
#pragma unroll
      for (int i = 0; i < 4; i++) {
        af[i][0] = *(const bf16x8*)&lan[aBase + i * 1024 + bir0];
        af[i][1] = *(const bf16x8*)&lan[aBase + i * 1024 + bir1];
      }
#pragma unroll
      for (int j = 0; j < 2; j++) {
        b01[j][0] = *(const bf16x8*)&lbn[bBase + j * 1024 + bir0];
        b01[j][1] = *(const bf16x8*)&lbn[bBase + j * 1024 + bir1];
      }
    }
  }
#undef STG_A
#undef STG_B

  // ---------------- epilogue ----------------
  float bias_r[6];
#pragma unroll
  for (int fj = 0; fj < 6; fj++) {
    int cl = wn * 96 + fj * 16 + lo;
    bias_r[fj] = biasP[(cl >> 6) * 512 + nb * 64 + (cl & 63)];
  }
#pragma unroll
  for (int fi = 0; fi < 4; fi++) {
#pragma unroll
    for (int fj = 0; fj < 6; fj++) {
      int cl = wn * 96 + fj * 16 + lo;
      int r  = wm * 64 + fi * 16 + hi * 4;
      float v0 = acc[fi][fj][0] + bias_r[fj];
      float v1 = acc[fi][fj][1] + bias_r[fj];
      float v2 = acc[fi][fj][2] + bias_r[fj];
      float v3 = acc[fi][fj][3] + bias_r[fj];
      unsigned int u01 = (unsigned int)bfc(v0) | ((unsigned int)bfc(v1) << 16);
      unsigned int u23 = (unsigned int)bfc(v2) | ((unsigned int)bfc(v3) << 16);
      *(unsigned int*)&Xt[cl * LDP + r]     = u01;
      *(unsigned int*)&Xt[cl * LDP + r + 2] = u23;
    }
  }
  __syncthreads();

  // segment maxes: seg chunk = Xt cols 0..63
  if (tid < 256) {
    int seg = tid >> 6, c = tid & 63;
    int base = c * LDP + seg * 64;
    float m = -1e30f;
#pragma unroll
    for (int k = 0; k < 32; k++) {
      unsigned int u = *(const unsigned int*)&Xt[base + 2 * k];
      m = fmaxf(m, fmaxf(bflo(u), bfhi(u)));
    }
    segred[seg * 64 + c] = m;
  }
  __syncthreads();

  // final combine: wave wv owns rows wv*32..+31, lane = col c (0..63)
  {
    int c  = lane;
    int r0 = wv * 32;
    int b  = mb >> 4;
    int gcol = nb * 64 + c;
    float g = ctx[b * 512 + gcol] + segred[(r0 >> 6) * 64 + c];
    int lbase = (64 + c) * LDP;
    int obase = (128 + c) * LDP;
    float lw0 = bf1(Xt[lbase + max(r0 - 2, 0)]);
    float lw1 = bf1(Xt[lbase + max(r0 - 1, 0)]);
    float lw2 = bf1(Xt[lbase + r0]);
    float lw3 = bf1(Xt[lbase + r0 + 1]);
    size_t obase_g = ((size_t)(mb * 256 + r0)) * 512 + gcol;
#pragma unroll
    for (int j = 0; j < 32; j++) {
      int rn = min(r0 + j + 2, 255);
      float lw4 = bf1(Xt[lbase + rn]);
      float lm = fmaxf(fmaxf(fmaxf(lw0, lw1), fmaxf(lw2, lw3)), lw4);
      float o = bf1(Xt[obase + r0 + j]);
      out[obase_g + (size_t)j * 512] = g * o + lm;
      lw0 = lw1; lw1 = lw2; lw2 = lw3; lw3 = lw4;
    }
  }

  // side buffers for tile-boundary loc-window fixup (rows 0,1,254,255)
  if (tid < 256) {
    int rsel = tid >> 6, c = tid & 63;
    int r = (rsel < 2) ? rsel : (252 + rsel);   // 0,1,254,255
    int b = mb >> 4;
    float g = ctx[b * 512 + nb * 64 + c] + segred[(r >> 6) * 64 + c];
    float o = bf1(Xt[(128 + c) * LDP + r]);
    int gr = mb * 4 + rsel;
    sideLoc[gr * 512 + nb * 64 + c] = Xt[(64 + c) * LDP + r];
    sideGO[gr * 512 + nb * 64 + c]  = g * o;
  }
}

// ---------- K9: fixup for loc windows crossing 256-row tile boundaries ----------
__global__ void fixup_kernel(const unsigned short* __restrict__ sideLoc,
                             const float* __restrict__ sideGO,
                             float* __restrict__ out) {
  int rb = blockIdx.x;      // 0..63
  int tb = rb & 15;         // tile index within b
  int t = threadIdx.x;      // 256
  int rsel = t >> 6, cq = t & 63;
#pragma unroll
  for (int k = 0; k < 8; k++) {
    int c = cq * 8 + k;
    float miss;
    int rl;
    if (rsel == 0) {
      if (tb == 0) continue;
      miss = fmaxf(bf1(sideLoc[((rb - 1) * 4 + 2) * 512 + c]),
                   bf1(sideLoc[((rb - 1) * 4 + 3) * 512 + c]));
      rl = 0;
    } else if (rsel == 1) {
      if (tb == 0) continue;
      miss = bf1(sideLoc[((rb - 1) * 4 + 3) * 512 + c]);
      rl = 1;
    } else if (rsel == 2) {
      if (tb == 15) continue;
      miss = bf1(sideLoc[((rb + 1) * 4 + 0) * 512 + c]);
      rl = 254;
    } else {
      if (tb == 15) continue;
      miss = fmaxf(bf1(sideLoc[((rb + 1) * 4 + 0) * 512 + c]),
                   bf1(sideLoc[((rb + 1) * 4 + 1) * 512 + c]));
      rl = 255;
    }
    size_t oi = ((size_t)rb * 256 + rl) * 512 + c;
    float cand = sideGO[(rb * 4 + rsel) * 512 + c] + miss;
    out[oi] = fmaxf(out[oi], cand);
  }
}

// ---------- launch ----------
extern "C" void kernel_launch(void* const* d_in, const int* in_sizes, int n_in,
                              void* d_out, int out_size, void* d_ws, size_t ws_size,
                              hipStream_t stream) {
  const float* inp  = (const float*)d_in[0];
  const float* W    = (const float*)d_in[1];
  const float* bias = (const float*)d_in[2];
  float* out = (float*)d_out;
  char* ws = (char*)d_ws;

  const size_t INP_OFF  = 0;                   // bf16 inp: 33,554,432
  const size_t W_OFF    = 33554432;            // bf16 W[1536:3072]: 3,145,728
  const size_t MU_OFF   = 36700160;            // f32 mu: 16,384
  const size_t U_OFF    = MU_OFF + 16384;
  const size_t V_OFF    = U_OFF + 16384;
  const size_t CV_OFF   = V_OFF + 16384;       // 256
  const size_t AGG_OFF  = CV_OFF + 256;        // 8,192
  const size_t CTX_OFF  = AGG_OFF + 8192;      // 8,192
  const size_t SC_OFF   = CTX_OFF + 8192;      // 65,536
  const size_t SL_OFF   = SC_OFF + 65536;      // sideLoc bf16: 262,144
  const size_t SG_OFF   = SL_OFF + 262144;     // sideGO f32: 524,288

  unsigned short* inp_bf = (unsigned short*)(ws + INP_OFF);
  unsigned short* w_bf   = (unsigned short*)(ws + W_OFF);
  float* mu     = (float*)(ws + MU_OFF);
  float* u      = (float*)(ws + U_OFF);
  float* v      = (float*)(ws + V_OFF);
  float* cvec   = (float*)(ws + CV_OFF);
  float* agg    = (float*)(ws + AGG_OFF);
  float* ctx    = (float*)(ws + CTX_OFF);
  float* scores = (float*)(ws + SC_OFF);
  unsigned short* sideLoc = (unsigned short*)(ws + SL_OFF);
  float* sideGO = (float*)(ws + SG_OFF);

  hipFuncSetAttribute(reinterpret_cast<const void*>(gemm_fused),
                      hipFuncAttributeMaxDynamicSharedMemorySize, 114688);

  hipMemsetAsync(ws + MU_OFF, 0, 3 * 16384 + 256, stream);  // zero mu, u, v, cvec
  convert_mean_kernel<<<512, 256, 0, stream>>>(inp, W, inp_bf, w_bf, mu);
  agg_kernel<<<512, 256, 0, stream>>>(mu, W, bias, agg);
  v_kernel<<<dim3(4, 8), 256, 0, stream>>>(agg, W, bias, v, cvec);
  scores_kernel<<<4096, 256, 0, stream>>>(inp_bf, v, cvec, scores);
  softmax_kernel<<<4, 256, 0, stream>>>(scores);
  u_kernel<<<dim3(32, 2, 4), 256, 0, stream>>>(inp_bf, scores, u);
  ctx_kernel<<<512, 256, 0, stream>>>(u, W, bias, ctx);
  gemm_fused<<<512, 512, 114688, stream>>>((const __hip_bfloat16*)inp_bf,
                                           (const __hip_bfloat16*)w_bf,
                                           bias + 3 * A_, ctx, out, sideLoc, sideGO);
  fixup_kernel<<<64, 256, 0, stream>>>(sideLoc, sideGO, out);
}